// Round 7
// baseline (577.273 us; speedup 1.0000x reference)
//
#include <hip/hip_runtime.h>

#define N_  30000
#define E_  480000

typedef short short8 __attribute__((ext_vector_type(8)));
typedef float f32x4  __attribute__((ext_vector_type(4)));
typedef unsigned int u32x4 __attribute__((ext_vector_type(4)));
union Frag { u32x4 q; short8 v; unsigned short us[8]; };

__device__ __forceinline__ float b2f(unsigned short u){
  union { unsigned int i; float f; } v; v.i = ((unsigned int)u) << 16; return v.f;
}
__device__ __forceinline__ unsigned short f2b(float f){
  union { float f; unsigned int u; } v; v.f = f;
  unsigned int u = v.u;
  return (unsigned short)((u + 0x7fffu + ((u >> 16) & 1u)) >> 16);
}

// ---- init scratch ----
__global__ void k_init(int* counts, int* cursor, float* gsum, float* gsq){
  int i = blockIdx.x * 256 + threadIdx.x;
  if (i < N_){ counts[i] = 0; cursor[i] = 0; }
  if (i < 512){ gsum[i] = 0.0f; gsq[i] = 0.0f; }
}

// ---- convert + transpose weights fp32 -> bf16 ----
// Wt[c][k]    c:0..1023 (0..511 = W_fc col, 512..1023 = W_res col), k:0..127
// WtOut[n][k] n:0..127, k:0..511
__global__ void k_conv(const float* __restrict__ Wfc, const float* __restrict__ Wres,
                       const float* __restrict__ Wout,
                       unsigned short* __restrict__ Wt, unsigned short* __restrict__ WtOut){
  int gid = blockIdx.x * 256 + threadIdx.x;
  const int total1 = 1024 * 128;
  const int total2 = 128 * 512;
  for (int i = gid; i < total1 + total2; i += gridDim.x * 256){
    if (i < total1){
      int c = i >> 7, k = i & 127;
      float v = (c < 512) ? Wfc[k * 512 + c] : Wres[k * 512 + (c - 512)];
      Wt[c * 128 + k] = f2b(v);
    } else {
      int j = i - total1;
      int n = j >> 9, k = j & 511;
      WtOut[n * 512 + k] = f2b(Wout[k * 128 + n]);
    }
  }
}

// ---- histogram of dst ----
__global__ void k_hist(const int* __restrict__ dst, int* __restrict__ counts){
  int e = blockIdx.x * 256 + threadIdx.x;
  if (e < E_) atomicAdd(&counts[dst[e]], 1);
}

// ---- exclusive scan -> offs[0..N_] (single block) ----
__global__ void k_scan(const int* __restrict__ counts, int* __restrict__ offs){
  __shared__ int lds[1024];
  __shared__ int run_s;
  int t = threadIdx.x;
  if (t == 0) run_s = 0;
  __syncthreads();
  for (int base = 0; base < N_; base += 1024){
    int v = (base + t < N_) ? counts[base + t] : 0;
    lds[t] = v;
    __syncthreads();
    for (int s = 1; s < 1024; s <<= 1){
      int x = (t >= s) ? lds[t - s] : 0;
      __syncthreads();
      lds[t] += x;
      __syncthreads();
    }
    int incl = lds[t];
    if (base + t < N_) offs[base + t] = run_s + incl - v;
    __syncthreads();
    if (t == 1023) run_s += incl;
    __syncthreads();
  }
  if (t == 0) offs[N_] = run_s;
}

// ---- GEMM1 (MFMA): comb[n][0..511]=feat@W_fc, [512..1023]=feat@W_res, bf16 out
// grid ((N+63)/64, 8): 64 rows x 128 cols per block.
__global__ __launch_bounds__(256) void k_gemm1(const float* __restrict__ feat,
                                               const unsigned short* __restrict__ Wt,
                                               unsigned short* __restrict__ comb){
  int tid = threadIdx.x;
  int wave = tid >> 6, lane = tid & 63;
  int lrow = lane & 15, quad = lane >> 4;
  int rowbase = blockIdx.x * 64 + wave * 16;
  int colbase = blockIdx.y * 128;
  int arow = rowbase + lrow; if (arow > N_ - 1) arow = N_ - 1;
  const float* aptr = feat + arow * 128 + quad * 8;
  f32x4 acc[8] = {};
#pragma unroll
  for (int kk = 0; kk < 4; kk++){
    const f32x4* ap = reinterpret_cast<const f32x4*>(aptr + kk * 32);
    f32x4 a0 = ap[0], a1 = ap[1];
    Frag a;
#pragma unroll
    for (int i = 0; i < 4; i++){ a.us[i] = f2b(a0[i]); a.us[4 + i] = f2b(a1[i]); }
#pragma unroll
    for (int s = 0; s < 8; s++){
      int col = colbase + s * 16 + lrow;
      Frag b; b.q = *reinterpret_cast<const u32x4*>(Wt + col * 128 + kk * 32 + quad * 8);
      acc[s] = __builtin_amdgcn_mfma_f32_16x16x32_bf16(a.v, b.v, acc[s], 0, 0, 0);
    }
  }
#pragma unroll
  for (int s = 0; s < 8; s++){
    int col = colbase + s * 16 + lrow;
#pragma unroll
    for (int j = 0; j < 4; j++){
      int gr = rowbase + quad * 4 + j;   // C/D: col=lane&15, row=quad*4+reg (P1-verified)
      if (gr < N_) comb[gr * 1024 + col] = f2b(acc[s][j]);
    }
  }
}

// ---- el/er: one wave per node ----
__global__ __launch_bounds__(256) void k_elr(const unsigned short* __restrict__ comb,
                                             const float* __restrict__ al,
                                             const float* __restrict__ ar,
                                             float* __restrict__ el, float* __restrict__ er){
  int wave = threadIdx.x >> 6, lane = threadIdx.x & 63;
  int n = blockIdx.x * 4 + wave;
  if (n >= N_) return;
  Frag h; h.q = *reinterpret_cast<const u32x4*>(comb + n * 1024 + lane * 8);
  const f32x4* lp = reinterpret_cast<const f32x4*>(al + lane * 8);
  const f32x4* rp = reinterpret_cast<const f32x4*>(ar + lane * 8);
  f32x4 l0 = lp[0], l1 = lp[1], r0 = rp[0], r1 = rp[1];
  float sl = 0.f, sr = 0.f;
#pragma unroll
  for (int i = 0; i < 4; i++){
    float h0 = b2f(h.us[i]), h1 = b2f(h.us[4 + i]);
    sl += h0 * l0[i] + h1 * l1[i];
    sr += h0 * r0[i] + h1 * r1[i];
  }
  for (int o = 8; o >= 1; o >>= 1){
    sl += __shfl_down(sl, o, 16);
    sr += __shfl_down(sr, o, 16);
  }
  if ((lane & 15) == 0){
    int hd = lane >> 4;
    el[n * 4 + hd] = sl;
    er[n * 4 + hd] = sr;
  }
}

// ---- per-edge score (leaky relu) + CSR scatter ----
__global__ void k_edge(const int* __restrict__ src, const int* __restrict__ dst,
                       const float* __restrict__ el, const float* __restrict__ er,
                       float* __restrict__ escore, const int* __restrict__ offs,
                       int* __restrict__ cursor, int* __restrict__ eid){
  int e = blockIdx.x * 256 + threadIdx.x;
  if (e >= E_) return;
  int s = src[e], d = dst[e];
  f32x4 a = *reinterpret_cast<const f32x4*>(el + s * 4);
  f32x4 b = *reinterpret_cast<const f32x4*>(er + d * 4);
  f32x4 v = a + b;
#pragma unroll
  for (int i = 0; i < 4; i++) v[i] = v[i] > 0.f ? v[i] : 0.2f * v[i];
  *reinterpret_cast<f32x4*>(escore + e * 4) = v;
  int p = atomicAdd(&cursor[d], 1);
  eid[offs[d] + p] = e;
}

// ---- per-dst softmax + gather; rst into res half of comb ----
__global__ __launch_bounds__(256) void k_aggr(const int* __restrict__ offs,
                                              const int* __restrict__ eid,
                                              const int* __restrict__ src,
                                              const float* __restrict__ escore,
                                              unsigned short* __restrict__ comb,
                                              const float* __restrict__ bias){
  __shared__ float red[256];
  __shared__ float sm[4], sd[4];
  int n = blockIdx.x, t = threadIdx.x;
  int head = t >> 6, lane = t & 63;
  int off0 = offs[n], g = offs[n + 1] - off0;

  float m = -1e30f;
  for (int i = lane; i < g; i += 64)
    m = fmaxf(m, escore[eid[off0 + i] * 4 + head]);
  red[t] = m;
  __syncthreads();
  for (int s = 32; s > 0; s >>= 1){
    if (lane < s) red[t] = fmaxf(red[t], red[t + s]);
    __syncthreads();
  }
  if (lane == 0) sm[head] = red[t];
  __syncthreads();
  float em = sm[head];

  float ss = 0.0f;
  for (int i = lane; i < g; i += 64)
    ss += __expf(escore[eid[off0 + i] * 4 + head] - em);
  red[t] = ss;
  __syncthreads();
  for (int s = 32; s > 0; s >>= 1){
    if (lane < s) red[t] += red[t + s];
    __syncthreads();
  }
  if (lane == 0) sd[head] = (red[t] > 0.0f) ? 1.0f / red[t] : 0.0f;
  __syncthreads();
  float rd = sd[head];

  int c0 = t * 2;
  float f0 = 0.0f, f1 = 0.0f;
  for (int i = 0; i < g; i++){
    int e = eid[off0 + i];
    int sv = src[e];
    float a = __expf(escore[e * 4 + head] - em) * rd;
    unsigned int pv = *(const unsigned int*)(comb + sv * 1024 + c0);
    f0 += a * b2f((unsigned short)(pv & 0xffffu));
    f1 += a * b2f((unsigned short)(pv >> 16));
  }
  unsigned short* rp = comb + n * 1024 + 512 + c0;
  float r0 = f0 + b2f(rp[0]) + bias[c0];
  float r1 = f1 + b2f(rp[1]) + bias[c0 + 1];
  rp[0] = f2b(r0); rp[1] = f2b(r1);
}

// ---- BN stats ----
__global__ void k_stats(const unsigned short* __restrict__ comb,
                        float* __restrict__ gsum, float* __restrict__ gsq){
  int t = threadIdx.x;
  int r0 = blockIdx.x * 256;
  float s = 0.0f, q = 0.0f;
  for (int r = 0; r < 256; r++){
    int row = r0 + r;
    if (row < N_){
      float v = b2f(comb[row * 1024 + 512 + t]);
      s += v; q += v * v;
    }
  }
  atomicAdd(&gsum[t], s);
  atomicAdd(&gsq[t], q);
}

// ---- finalize BN affine ----
__global__ void k_bnfin(const float* __restrict__ gsum, const float* __restrict__ gsq,
                        const float* __restrict__ gamma, const float* __restrict__ beta,
                        float* __restrict__ scale, float* __restrict__ shift){
  int t = threadIdx.x;
  if (t < 512){
    float mu  = gsum[t] / (float)N_;
    float var = gsq[t] / (float)N_ - mu * mu;
    float inv = rsqrtf(var + 1e-5f);
    float sc  = gamma[t] * inv;
    scale[t] = sc;
    shift[t] = beta[t] - mu * sc;
  }
}

// ---- GEMM2 (MFMA): out = relu(BN(rst)) @ W_out + b_out, FP32 out ----
__global__ __launch_bounds__(256) void k_gemm2(const unsigned short* __restrict__ comb,
                                               const unsigned short* __restrict__ WtOut,
                                               const float* __restrict__ scale,
                                               const float* __restrict__ shift,
                                               const float* __restrict__ bout,
                                               float* __restrict__ out){
  __shared__ float sc[512], sh[512], bo[128];
  int t = threadIdx.x;
  for (int i = t; i < 512; i += 256){ sc[i] = scale[i]; sh[i] = shift[i]; }
  if (t < 128) bo[t] = bout[t];
  __syncthreads();
  int wave = t >> 6, lane = t & 63, lrow = lane & 15, quad = lane >> 4;
  int rowbase = blockIdx.x * 64 + wave * 16;
  int rr = rowbase + lrow; if (rr > N_ - 1) rr = N_ - 1;
  const unsigned short* arow = comb + rr * 1024 + 512;
  f32x4 acc[8] = {};
#pragma unroll
  for (int kk = 0; kk < 16; kk++){
    int base = kk * 32 + quad * 8;
    Frag a; a.q = *reinterpret_cast<const u32x4*>(arow + base);
#pragma unroll
    for (int i = 0; i < 8; i++){
      float x = b2f(a.us[i]);
      x = fmaf(x, sc[base + i], sh[base + i]);
      a.us[i] = f2b(fmaxf(x, 0.0f));
    }
#pragma unroll
    for (int s = 0; s < 8; s++){
      int col = s * 16 + lrow;
      Frag b; b.q = *reinterpret_cast<const u32x4*>(WtOut + col * 512 + base);
      acc[s] = __builtin_amdgcn_mfma_f32_16x16x32_bf16(a.v, b.v, acc[s], 0, 0, 0);
    }
  }
#pragma unroll
  for (int s = 0; s < 8; s++){
    int col = s * 16 + lrow;
    float bb = bo[col];
#pragma unroll
    for (int j = 0; j < 4; j++){
      int gr = rowbase + quad * 4 + j;
      if (gr < N_) out[gr * 128 + col] = acc[s][j] + bb;   // fp32 output
    }
  }
}

extern "C" void kernel_launch(void* const* d_in, const int* in_sizes, int n_in,
                              void* d_out, int out_size, void* d_ws, size_t ws_size,
                              hipStream_t stream){
  // fp32 inputs (hex-verified r4), FP32 output (reference dtype; r5/r6 √2-decorrelation
  // signature showed the harness reads d_out as float*)
  const float* feat  = (const float*)d_in[0];
  const int*   src   = (const int*)d_in[1];
  const int*   dst   = (const int*)d_in[2];
  const float* Wfc   = (const float*)d_in[3];
  const float* al    = (const float*)d_in[4];
  const float* ar    = (const float*)d_in[5];
  const float* Wres  = (const float*)d_in[6];
  const float* bias  = (const float*)d_in[7];
  const float* gamma = (const float*)d_in[8];
  const float* beta  = (const float*)d_in[9];
  const float* Wout  = (const float*)d_in[10];
  const float* bout  = (const float*)d_in[11];
  float* out = (float*)d_out;

  char* ws = (char*)d_ws;
  unsigned short* comb   = (unsigned short*)(ws + 0);          // 61,440,000 B
  unsigned short* Wt     = (unsigned short*)(ws + 61440000);   //    262,144
  unsigned short* WtOut  = (unsigned short*)(ws + 61702144);   //    131,072
  float*          el     = (float*)(ws + 61833216);            //    480,000
  float*          er     = (float*)(ws + 62313216);            //    480,000
  float*          escore = (float*)(ws + 62793216);            //  7,680,000
  int*            offs   = (int*)(ws + 70473216);              //    120,064 (pad)
  int*            counts = (int*)(ws + 70593280);              //    120,064 (pad)
  int*            cursor = (int*)(ws + 70713344);              //    120,064 (pad)
  int*            eid    = (int*)(ws + 70833408);              //  1,920,000
  float*          gsum   = (float*)(ws + 72753408);
  float*          gsq    = (float*)(ws + 72755456);
  float*          scale  = (float*)(ws + 72757504);
  float*          shift  = (float*)(ws + 72759552);

  k_init<<<(N_ + 255) / 256, 256, 0, stream>>>(counts, cursor, gsum, gsq);
  k_conv<<<640, 256, 0, stream>>>(Wfc, Wres, Wout, Wt, WtOut);
  k_hist<<<(E_ + 255) / 256, 256, 0, stream>>>(dst, counts);
  k_scan<<<1, 1024, 0, stream>>>(counts, offs);
  dim3 g1((N_ + 63) / 64, 8);
  k_gemm1<<<g1, 256, 0, stream>>>(feat, Wt, comb);
  k_elr<<<(N_ + 3) / 4, 256, 0, stream>>>(comb, al, ar, el, er);
  k_edge<<<(E_ + 255) / 256, 256, 0, stream>>>(src, dst, el, er, escore, offs, cursor, eid);
  k_aggr<<<N_, 256, 0, stream>>>(offs, eid, src, escore, comb, bias);
  k_stats<<<(N_ + 255) / 256, 512, 0, stream>>>(comb, gsum, gsq);
  k_bnfin<<<1, 512, 0, stream>>>(gsum, gsq, gamma, beta, scale, shift);
  k_gemm2<<<(N_ + 63) / 64, 256, 0, stream>>>(comb, WtOut, scale, shift, bout, out);
}

// Round 8
// 470.413 us; speedup vs baseline: 1.2272x; 1.2272x over previous
//
#include <hip/hip_runtime.h>

#define N_  30000
#define E_  480000

typedef short short8 __attribute__((ext_vector_type(8)));
typedef float f32x4  __attribute__((ext_vector_type(4)));
typedef unsigned int u32x4 __attribute__((ext_vector_type(4)));
union Frag { u32x4 q; short8 v; unsigned short us[8]; };

__device__ __forceinline__ float b2f(unsigned short u){
  union { unsigned int i; float f; } v; v.i = ((unsigned int)u) << 16; return v.f;
}
__device__ __forceinline__ unsigned short f2b(float f){
  union { float f; unsigned int u; } v; v.f = f;
  unsigned int u = v.u;
  return (unsigned short)((u + 0x7fffu + ((u >> 16) & 1u)) >> 16);
}

// ---- init scratch ----
__global__ void k_init(int* counts, int* cursor, float* gsum, float* gsq){
  int i = blockIdx.x * 256 + threadIdx.x;
  if (i < N_){ counts[i] = 0; cursor[i] = 0; }
  if (i < 512){ gsum[i] = 0.0f; gsq[i] = 0.0f; }
}

// ---- convert + transpose weights fp32 -> bf16 ----
__global__ void k_conv(const float* __restrict__ Wfc, const float* __restrict__ Wres,
                       const float* __restrict__ Wout,
                       unsigned short* __restrict__ Wt, unsigned short* __restrict__ WtOut){
  int gid = blockIdx.x * 256 + threadIdx.x;
  const int total1 = 1024 * 128;
  const int total2 = 128 * 512;
  for (int i = gid; i < total1 + total2; i += gridDim.x * 256){
    if (i < total1){
      int c = i >> 7, k = i & 127;
      float v = (c < 512) ? Wfc[k * 512 + c] : Wres[k * 512 + (c - 512)];
      Wt[c * 128 + k] = f2b(v);
    } else {
      int j = i - total1;
      int n = j >> 9, k = j & 511;
      WtOut[n * 512 + k] = f2b(Wout[k * 128 + n]);
    }
  }
}

// ---- histogram of dst ----
__global__ void k_hist(const int* __restrict__ dst, int* __restrict__ counts){
  int e = blockIdx.x * 256 + threadIdx.x;
  if (e < E_) atomicAdd(&counts[dst[e]], 1);
}

// ---- exclusive scan -> offs[0..N_]: 1 block, register-serial + shuffle ----
// thread t owns counts[t*32 .. t*32+32); 2 barriers total.
__global__ __launch_bounds__(1024) void k_scan(const int* __restrict__ counts,
                                               int* __restrict__ offs){
  __shared__ int wsum[16];
  int t = threadIdx.x;
  int lane = t & 63, w = t >> 6;
  int base = t * 32;
  int vals[32];
  int s = 0;
#pragma unroll
  for (int j = 0; j < 32; j++){
    int idx = base + j;
    int v = (idx < N_) ? counts[idx] : 0;
    vals[j] = s;           // local exclusive prefix
    s += v;
  }
  // inclusive scan of s across the wave
  int x = s;
  for (int o = 1; o < 64; o <<= 1){
    int y = __shfl_up(x, o);
    if (lane >= o) x += y;
  }
  if (lane == 63) wsum[w] = x;
  __syncthreads();
  if (t < 16){
    int y = wsum[t];
    for (int o = 1; o < 16; o <<= 1){
      int z = __shfl_up(y, o, 16);
      if (t >= o) y += z;
    }
    wsum[t] = y;           // inclusive wave sums
  }
  __syncthreads();
  int wbase = (w > 0) ? wsum[w - 1] : 0;
  int ex = wbase + x - s;  // exclusive prefix of this thread's chunk
#pragma unroll
  for (int j = 0; j < 32; j++){
    int idx = base + j;
    if (idx <= N_) offs[idx] = ex + vals[j];
  }
}

// ---- GEMM1 (MFMA): comb[n][0..511]=feat@W_fc, [512..1023]=feat@W_res, bf16 out
__global__ __launch_bounds__(256) void k_gemm1(const float* __restrict__ feat,
                                               const unsigned short* __restrict__ Wt,
                                               unsigned short* __restrict__ comb){
  int tid = threadIdx.x;
  int wave = tid >> 6, lane = tid & 63;
  int lrow = lane & 15, quad = lane >> 4;
  int rowbase = blockIdx.x * 64 + wave * 16;
  int colbase = blockIdx.y * 128;
  int arow = rowbase + lrow; if (arow > N_ - 1) arow = N_ - 1;
  const float* aptr = feat + arow * 128 + quad * 8;
  f32x4 acc[8] = {};
#pragma unroll
  for (int kk = 0; kk < 4; kk++){
    const f32x4* ap = reinterpret_cast<const f32x4*>(aptr + kk * 32);
    f32x4 a0 = ap[0], a1 = ap[1];
    Frag a;
#pragma unroll
    for (int i = 0; i < 4; i++){ a.us[i] = f2b(a0[i]); a.us[4 + i] = f2b(a1[i]); }
#pragma unroll
    for (int s = 0; s < 8; s++){
      int col = colbase + s * 16 + lrow;
      Frag b; b.q = *reinterpret_cast<const u32x4*>(Wt + col * 128 + kk * 32 + quad * 8);
      acc[s] = __builtin_amdgcn_mfma_f32_16x16x32_bf16(a.v, b.v, acc[s], 0, 0, 0);
    }
  }
#pragma unroll
  for (int s = 0; s < 8; s++){
    int col = colbase + s * 16 + lrow;
#pragma unroll
    for (int j = 0; j < 4; j++){
      int gr = rowbase + quad * 4 + j;
      if (gr < N_) comb[gr * 1024 + col] = f2b(acc[s][j]);
    }
  }
}

// ---- el/er: one wave per node ----
__global__ __launch_bounds__(256) void k_elr(const unsigned short* __restrict__ comb,
                                             const float* __restrict__ al,
                                             const float* __restrict__ ar,
                                             float* __restrict__ el, float* __restrict__ er){
  int wave = threadIdx.x >> 6, lane = threadIdx.x & 63;
  int n = blockIdx.x * 4 + wave;
  if (n >= N_) return;
  Frag h; h.q = *reinterpret_cast<const u32x4*>(comb + n * 1024 + lane * 8);
  const f32x4* lp = reinterpret_cast<const f32x4*>(al + lane * 8);
  const f32x4* rp = reinterpret_cast<const f32x4*>(ar + lane * 8);
  f32x4 l0 = lp[0], l1 = lp[1], r0 = rp[0], r1 = rp[1];
  float sl = 0.f, sr = 0.f;
#pragma unroll
  for (int i = 0; i < 4; i++){
    float h0 = b2f(h.us[i]), h1 = b2f(h.us[4 + i]);
    sl += h0 * l0[i] + h1 * l1[i];
    sr += h0 * r0[i] + h1 * r1[i];
  }
  for (int o = 8; o >= 1; o >>= 1){
    sl += __shfl_down(sl, o, 16);
    sr += __shfl_down(sr, o, 16);
  }
  if ((lane & 15) == 0){
    int hd = lane >> 4;
    el[n * 4 + hd] = sl;
    er[n * 4 + hd] = sr;
  }
}

// ---- per-edge score (leaky relu) + CSR scatter ----
__global__ void k_edge(const int* __restrict__ src, const int* __restrict__ dst,
                       const float* __restrict__ el, const float* __restrict__ er,
                       float* __restrict__ escore, const int* __restrict__ offs,
                       int* __restrict__ cursor, int* __restrict__ eid){
  int e = blockIdx.x * 256 + threadIdx.x;
  if (e >= E_) return;
  int s = src[e], d = dst[e];
  f32x4 a = *reinterpret_cast<const f32x4*>(el + s * 4);
  f32x4 b = *reinterpret_cast<const f32x4*>(er + d * 4);
  f32x4 v = a + b;
#pragma unroll
  for (int i = 0; i < 4; i++) v[i] = v[i] > 0.f ? v[i] : 0.2f * v[i];
  *reinterpret_cast<f32x4*>(escore + e * 4) = v;
  int p = atomicAdd(&cursor[d], 1);
  eid[offs[d] + p] = e;
}

// ---- per-dst softmax + gather: ONE WAVE PER NODE, no barriers ----
// lane owns channels [lane*8, lane*8+8); head = lane>>4 (channel block matches).
__global__ __launch_bounds__(256) void k_aggr(const int* __restrict__ offs,
                                              const int* __restrict__ eid,
                                              const int* __restrict__ src,
                                              const float* __restrict__ escore,
                                              unsigned short* __restrict__ comb,
                                              const float* __restrict__ bias){
  int wave = threadIdx.x >> 6, lane = threadIdx.x & 63;
  int n = blockIdx.x * 4 + wave;
  if (n >= N_) return;
  int head = lane >> 4, sub = lane & 15;
  int off0 = offs[n], g = offs[n + 1] - off0;

  // phase 1: per-head max then sum-of-exp (16-lane groups)
  float m = -1e30f;
  for (int i = sub; i < g; i += 16)
    m = fmaxf(m, escore[eid[off0 + i] * 4 + head]);
  for (int o = 8; o >= 1; o >>= 1) m = fmaxf(m, __shfl_xor(m, o, 16));
  float ss = 0.f;
  for (int i = sub; i < g; i += 16)
    ss += __expf(escore[eid[off0 + i] * 4 + head] - m);
  for (int o = 8; o >= 1; o >>= 1) ss += __shfl_xor(ss, o, 16);
  float rd = (ss > 0.f) ? 1.0f / ss : 0.f;

  // phase 2: weighted gather, 16 B/lane loads, eid/src prefetch pipeline
  int c0 = lane * 8;
  float acc[8] = {};
  int e = (g > 0) ? eid[off0] : 0;
  int sv = (g > 0) ? src[e] : 0;
  for (int i = 0; i < g; i++){
    int e_n = 0, sv_n = 0;
    if (i + 1 < g){ e_n = eid[off0 + i + 1]; sv_n = src[e_n]; }
    float scv = escore[e * 4 + head];
    u32x4 pv = *reinterpret_cast<const u32x4*>(comb + sv * 1024 + c0);
    float a = __expf(scv - m) * rd;
#pragma unroll
    for (int d = 0; d < 4; d++){
      acc[2 * d]     += a * b2f((unsigned short)(pv[d] & 0xffffu));
      acc[2 * d + 1] += a * b2f((unsigned short)(pv[d] >> 16));
    }
    e = e_n; sv = sv_n;
  }

  // residual + bias, write back into res half (becomes rst)
  unsigned short* rp = comb + n * 1024 + 512 + c0;
  u32x4 rv = *reinterpret_cast<const u32x4*>(rp);
  const f32x4* bp = reinterpret_cast<const f32x4*>(bias + c0);
  f32x4 b0 = bp[0], b1 = bp[1];
  u32x4 ov;
#pragma unroll
  for (int d = 0; d < 4; d++){
    float v0 = acc[2 * d]     + b2f((unsigned short)(rv[d] & 0xffffu)) + ((d < 2) ? b0[2 * d]     : b1[2 * d - 4]);
    float v1 = acc[2 * d + 1] + b2f((unsigned short)(rv[d] >> 16))     + ((d < 2) ? b0[2 * d + 1] : b1[2 * d - 3]);
    ov[d] = (unsigned int)f2b(v0) | ((unsigned int)f2b(v1) << 16);
  }
  *reinterpret_cast<u32x4*>(rp) = ov;
}

// ---- BN stats ----
__global__ void k_stats(const unsigned short* __restrict__ comb,
                        float* __restrict__ gsum, float* __restrict__ gsq){
  int t = threadIdx.x;
  int r0 = blockIdx.x * 256;
  float s = 0.0f, q = 0.0f;
  for (int r = 0; r < 256; r++){
    int row = r0 + r;
    if (row < N_){
      float v = b2f(comb[row * 1024 + 512 + t]);
      s += v; q += v * v;
    }
  }
  atomicAdd(&gsum[t], s);
  atomicAdd(&gsq[t], q);
}

// ---- finalize BN affine ----
__global__ void k_bnfin(const float* __restrict__ gsum, const float* __restrict__ gsq,
                        const float* __restrict__ gamma, const float* __restrict__ beta,
                        float* __restrict__ scale, float* __restrict__ shift){
  int t = threadIdx.x;
  if (t < 512){
    float mu  = gsum[t] / (float)N_;
    float var = gsq[t] / (float)N_ - mu * mu;
    float inv = rsqrtf(var + 1e-5f);
    float sc  = gamma[t] * inv;
    scale[t] = sc;
    shift[t] = beta[t] - mu * sc;
  }
}

// ---- GEMM2 (MFMA): out = relu(BN(rst)) @ W_out + b_out, fp32 out ----
__global__ __launch_bounds__(256) void k_gemm2(const unsigned short* __restrict__ comb,
                                               const unsigned short* __restrict__ WtOut,
                                               const float* __restrict__ scale,
                                               const float* __restrict__ shift,
                                               const float* __restrict__ bout,
                                               float* __restrict__ out){
  __shared__ float sc[512], sh[512], bo[128];
  int t = threadIdx.x;
  for (int i = t; i < 512; i += 256){ sc[i] = scale[i]; sh[i] = shift[i]; }
  if (t < 128) bo[t] = bout[t];
  __syncthreads();
  int wave = t >> 6, lane = t & 63, lrow = lane & 15, quad = lane >> 4;
  int rowbase = blockIdx.x * 64 + wave * 16;
  int rr = rowbase + lrow; if (rr > N_ - 1) rr = N_ - 1;
  const unsigned short* arow = comb + rr * 1024 + 512;
  f32x4 acc[8] = {};
#pragma unroll
  for (int kk = 0; kk < 16; kk++){
    int base = kk * 32 + quad * 8;
    Frag a; a.q = *reinterpret_cast<const u32x4*>(arow + base);
#pragma unroll
    for (int i = 0; i < 8; i++){
      float x = b2f(a.us[i]);
      x = fmaf(x, sc[base + i], sh[base + i]);
      a.us[i] = f2b(fmaxf(x, 0.0f));
    }
#pragma unroll
    for (int s = 0; s < 8; s++){
      int col = s * 16 + lrow;
      Frag b; b.q = *reinterpret_cast<const u32x4*>(WtOut + col * 512 + base);
      acc[s] = __builtin_amdgcn_mfma_f32_16x16x32_bf16(a.v, b.v, acc[s], 0, 0, 0);
    }
  }
#pragma unroll
  for (int s = 0; s < 8; s++){
    int col = s * 16 + lrow;
    float bb = bo[col];
#pragma unroll
    for (int j = 0; j < 4; j++){
      int gr = rowbase + quad * 4 + j;
      if (gr < N_) out[gr * 128 + col] = acc[s][j] + bb;
    }
  }
}

extern "C" void kernel_launch(void* const* d_in, const int* in_sizes, int n_in,
                              void* d_out, int out_size, void* d_ws, size_t ws_size,
                              hipStream_t stream){
  const float* feat  = (const float*)d_in[0];
  const int*   src   = (const int*)d_in[1];
  const int*   dst   = (const int*)d_in[2];
  const float* Wfc   = (const float*)d_in[3];
  const float* al    = (const float*)d_in[4];
  const float* ar    = (const float*)d_in[5];
  const float* Wres  = (const float*)d_in[6];
  const float* bias  = (const float*)d_in[7];
  const float* gamma = (const float*)d_in[8];
  const float* beta  = (const float*)d_in[9];
  const float* Wout  = (const float*)d_in[10];
  const float* bout  = (const float*)d_in[11];
  float* out = (float*)d_out;

  char* ws = (char*)d_ws;
  unsigned short* comb   = (unsigned short*)(ws + 0);          // 61,440,000 B
  unsigned short* Wt     = (unsigned short*)(ws + 61440000);
  unsigned short* WtOut  = (unsigned short*)(ws + 61702144);
  float*          el     = (float*)(ws + 61833216);
  float*          er     = (float*)(ws + 62313216);
  float*          escore = (float*)(ws + 62793216);
  int*            offs   = (int*)(ws + 70473216);
  int*            counts = (int*)(ws + 70593280);
  int*            cursor = (int*)(ws + 70713344);
  int*            eid    = (int*)(ws + 70833408);
  float*          gsum   = (float*)(ws + 72753408);
  float*          gsq    = (float*)(ws + 72755456);
  float*          scale  = (float*)(ws + 72757504);
  float*          shift  = (float*)(ws + 72759552);

  k_init<<<(N_ + 255) / 256, 256, 0, stream>>>(counts, cursor, gsum, gsq);
  k_conv<<<640, 256, 0, stream>>>(Wfc, Wres, Wout, Wt, WtOut);
  k_hist<<<(E_ + 255) / 256, 256, 0, stream>>>(dst, counts);
  k_scan<<<1, 1024, 0, stream>>>(counts, offs);
  dim3 g1((N_ + 63) / 64, 8);
  k_gemm1<<<g1, 256, 0, stream>>>(feat, Wt, comb);
  k_elr<<<(N_ + 3) / 4, 256, 0, stream>>>(comb, al, ar, el, er);
  k_edge<<<(E_ + 255) / 256, 256, 0, stream>>>(src, dst, el, er, escore, offs, cursor, eid);
  k_aggr<<<(N_ + 3) / 4, 256, 0, stream>>>(offs, eid, src, escore, comb, bias);
  k_stats<<<(N_ + 255) / 256, 512, 0, stream>>>(comb, gsum, gsq);
  k_bnfin<<<1, 512, 0, stream>>>(gsum, gsq, gamma, beta, scale, shift);
  k_gemm2<<<(N_ + 63) / 64, 256, 0, stream>>>(comb, WtOut, scale, shift, bout, out);
}

// Round 9
// 468.629 us; speedup vs baseline: 1.2318x; 1.0038x over previous
//
#include <hip/hip_runtime.h>

#define N_  30000
#define E_  480000

typedef short short8 __attribute__((ext_vector_type(8)));
typedef float f32x4  __attribute__((ext_vector_type(4)));
typedef unsigned int u32x4 __attribute__((ext_vector_type(4)));
union Frag { u32x4 q; short8 v; unsigned short us[8]; };

__device__ __forceinline__ float b2f(unsigned short u){
  union { unsigned int i; float f; } v; v.i = ((unsigned int)u) << 16; return v.f;
}
__device__ __forceinline__ unsigned short f2b(float f){
  union { float f; unsigned int u; } v; v.f = f;
  unsigned int u = v.u;
  return (unsigned short)((u + 0x7fffu + ((u >> 16) & 1u)) >> 16);
}

// ---- init scratch + convert/transpose weights (merged, independent work) ----
__global__ void k_initconv(const float* __restrict__ Wfc, const float* __restrict__ Wres,
                           const float* __restrict__ Wout,
                           unsigned short* __restrict__ Wt, unsigned short* __restrict__ WtOut,
                           int* __restrict__ counts, int* __restrict__ cursor,
                           float* __restrict__ gsum, float* __restrict__ gsq){
  int gid = blockIdx.x * 256 + threadIdx.x;
  if (gid < N_){ counts[gid] = 0; cursor[gid] = 0; }
  if (gid < 512){ gsum[gid] = 0.0f; gsq[gid] = 0.0f; }
  const int total1 = 1024 * 128;
  const int total2 = 128 * 512;
  for (int i = gid; i < total1 + total2; i += gridDim.x * 256){
    if (i < total1){
      int c = i >> 7, k = i & 127;
      float v = (c < 512) ? Wfc[k * 512 + c] : Wres[k * 512 + (c - 512)];
      Wt[c * 128 + k] = f2b(v);
    } else {
      int j = i - total1;
      int n = j >> 9, k = j & 511;
      WtOut[n * 512 + k] = f2b(Wout[k * 128 + n]);
    }
  }
}

// ---- histogram of dst ----
__global__ void k_hist(const int* __restrict__ dst, int* __restrict__ counts){
  int e = blockIdx.x * 256 + threadIdx.x;
  if (e < E_) atomicAdd(&counts[dst[e]], 1);
}

// ---- exclusive scan -> offs[0..N_]: 1 block, register-serial + shuffle ----
__global__ __launch_bounds__(1024) void k_scan(const int* __restrict__ counts,
                                               int* __restrict__ offs){
  __shared__ int wsum[16];
  int t = threadIdx.x;
  int lane = t & 63, w = t >> 6;
  int base = t * 32;
  int vals[32];
  int s = 0;
#pragma unroll
  for (int j = 0; j < 32; j++){
    int idx = base + j;
    int v = (idx < N_) ? counts[idx] : 0;
    vals[j] = s;
    s += v;
  }
  int x = s;
  for (int o = 1; o < 64; o <<= 1){
    int y = __shfl_up(x, o);
    if (lane >= o) x += y;
  }
  if (lane == 63) wsum[w] = x;
  __syncthreads();
  if (t < 16){
    int y = wsum[t];
    for (int o = 1; o < 16; o <<= 1){
      int z = __shfl_up(y, o, 16);
      if (t >= o) y += z;
    }
    wsum[t] = y;
  }
  __syncthreads();
  int wbase = (w > 0) ? wsum[w - 1] : 0;
  int ex = wbase + x - s;
#pragma unroll
  for (int j = 0; j < 32; j++){
    int idx = base + j;
    if (idx <= N_) offs[idx] = ex + vals[j];
  }
}

// ---- GEMM1 (MFMA) + fused el/er epilogue ----
// grid (469, 8): 64 rows x 128 cols/block. by<4 => head by of h (el/er computed here);
// by>=4 => W_res half.
__global__ __launch_bounds__(256) void k_gemm1(const float* __restrict__ feat,
                                               const unsigned short* __restrict__ Wt,
                                               const float* __restrict__ al,
                                               const float* __restrict__ ar,
                                               unsigned short* __restrict__ comb,
                                               float* __restrict__ el,
                                               float* __restrict__ er){
  int tid = threadIdx.x;
  int wave = tid >> 6, lane = tid & 63;
  int lrow = lane & 15, quad = lane >> 4;
  int rowbase = blockIdx.x * 64 + wave * 16;
  int colbase = blockIdx.y * 128;
  int arow = rowbase + lrow; if (arow > N_ - 1) arow = N_ - 1;
  const float* aptr = feat + arow * 128 + quad * 8;
  f32x4 acc[8] = {};
#pragma unroll
  for (int kk = 0; kk < 4; kk++){
    const f32x4* ap = reinterpret_cast<const f32x4*>(aptr + kk * 32);
    f32x4 a0 = ap[0], a1 = ap[1];
    Frag a;
#pragma unroll
    for (int i = 0; i < 4; i++){ a.us[i] = f2b(a0[i]); a.us[4 + i] = f2b(a1[i]); }
#pragma unroll
    for (int s = 0; s < 8; s++){
      int col = colbase + s * 16 + lrow;
      Frag b; b.q = *reinterpret_cast<const u32x4*>(Wt + col * 128 + kk * 32 + quad * 8);
      acc[s] = __builtin_amdgcn_mfma_f32_16x16x32_bf16(a.v, b.v, acc[s], 0, 0, 0);
    }
  }
#pragma unroll
  for (int s = 0; s < 8; s++){
    int col = colbase + s * 16 + lrow;
#pragma unroll
    for (int j = 0; j < 4; j++){
      int gr = rowbase + quad * 4 + j;
      if (gr < N_) comb[gr * 1024 + col] = f2b(acc[s][j]);
    }
  }
  // fused el/er: this block holds head h's full 128 channels for its 64 rows
  if (blockIdx.y < 4){
    int h = blockIdx.y;
    float pl[4] = {}, pr[4] = {};
#pragma unroll
    for (int s = 0; s < 8; s++){
      float av = al[h * 128 + s * 16 + lrow];
      float rv = ar[h * 128 + s * 16 + lrow];
#pragma unroll
      for (int j = 0; j < 4; j++){
        pl[j] += acc[s][j] * av;
        pr[j] += acc[s][j] * rv;
      }
    }
    for (int o = 8; o >= 1; o >>= 1){
#pragma unroll
      for (int j = 0; j < 4; j++){
        pl[j] += __shfl_down(pl[j], o, 16);
        pr[j] += __shfl_down(pr[j], o, 16);
      }
    }
    if (lrow == 0){
#pragma unroll
      for (int j = 0; j < 4; j++){
        int gr = rowbase + quad * 4 + j;
        if (gr < N_){ el[gr * 4 + h] = pl[j]; er[gr * 4 + h] = pr[j]; }
      }
    }
  }
}

// ---- per-edge score (leaky relu) + CSR scatter ----
__global__ void k_edge(const int* __restrict__ src, const int* __restrict__ dst,
                       const float* __restrict__ el, const float* __restrict__ er,
                       float* __restrict__ escore, const int* __restrict__ offs,
                       int* __restrict__ cursor, int* __restrict__ eid){
  int e = blockIdx.x * 256 + threadIdx.x;
  if (e >= E_) return;
  int s = src[e], d = dst[e];
  f32x4 a = *reinterpret_cast<const f32x4*>(el + s * 4);
  f32x4 b = *reinterpret_cast<const f32x4*>(er + d * 4);
  f32x4 v = a + b;
#pragma unroll
  for (int i = 0; i < 4; i++) v[i] = v[i] > 0.f ? v[i] : 0.2f * v[i];
  *reinterpret_cast<f32x4*>(escore + e * 4) = v;
  int p = atomicAdd(&cursor[d], 1);
  eid[offs[d] + p] = e;
}

// ---- per-dst softmax + gather: one wave per node, 4-way unrolled gather ----
__global__ __launch_bounds__(256) void k_aggr(const int* __restrict__ offs,
                                              const int* __restrict__ eid,
                                              const int* __restrict__ src,
                                              const float* __restrict__ escore,
                                              unsigned short* __restrict__ comb,
                                              const float* __restrict__ bias){
  int wave = threadIdx.x >> 6, lane = threadIdx.x & 63;
  int n = blockIdx.x * 4 + wave;
  if (n >= N_) return;
  int head = lane >> 4, sub = lane & 15;
  int off0 = offs[n], g = offs[n + 1] - off0;

  // per-head max and sum-of-exp (16-lane groups)
  float m = -1e30f;
  for (int i = sub; i < g; i += 16)
    m = fmaxf(m, escore[eid[off0 + i] * 4 + head]);
  for (int o = 8; o >= 1; o >>= 1) m = fmaxf(m, __shfl_xor(m, o, 16));
  float ss = 0.f;
  for (int i = sub; i < g; i += 16)
    ss += __expf(escore[eid[off0 + i] * 4 + head] - m);
  for (int o = 8; o >= 1; o >>= 1) ss += __shfl_xor(ss, o, 16);
  float rd = (ss > 0.f) ? 1.0f / ss : 0.f;

  // weighted gather: 4 independent chains in flight
  int c0 = lane * 8;
  float acc[8] = {};
  int i = 0;
  for (; i + 3 < g; i += 4){
    int ea = eid[off0 + i],     eb = eid[off0 + i + 1];
    int ec = eid[off0 + i + 2], ed = eid[off0 + i + 3];
    int sa = src[ea], sb = src[eb], sc2 = src[ec], sd = src[ed];
    float va = escore[ea * 4 + head], vb = escore[eb * 4 + head];
    float vc = escore[ec * 4 + head], vd = escore[ed * 4 + head];
    u32x4 pa = *reinterpret_cast<const u32x4*>(comb + sa * 1024 + c0);
    u32x4 pb = *reinterpret_cast<const u32x4*>(comb + sb * 1024 + c0);
    u32x4 pc = *reinterpret_cast<const u32x4*>(comb + sc2 * 1024 + c0);
    u32x4 pd = *reinterpret_cast<const u32x4*>(comb + sd * 1024 + c0);
    float aa = __expf(va - m) * rd, ab = __expf(vb - m) * rd;
    float ac2 = __expf(vc - m) * rd, ad = __expf(vd - m) * rd;
#pragma unroll
    for (int d = 0; d < 4; d++){
      acc[2*d]   += aa * b2f((unsigned short)(pa[d] & 0xffffu))
                  + ab * b2f((unsigned short)(pb[d] & 0xffffu))
                  + ac2 * b2f((unsigned short)(pc[d] & 0xffffu))
                  + ad * b2f((unsigned short)(pd[d] & 0xffffu));
      acc[2*d+1] += aa * b2f((unsigned short)(pa[d] >> 16))
                  + ab * b2f((unsigned short)(pb[d] >> 16))
                  + ac2 * b2f((unsigned short)(pc[d] >> 16))
                  + ad * b2f((unsigned short)(pd[d] >> 16));
    }
  }
  for (; i < g; i++){
    int e = eid[off0 + i];
    int sv = src[e];
    float a = __expf(escore[e * 4 + head] - m) * rd;
    u32x4 pv = *reinterpret_cast<const u32x4*>(comb + sv * 1024 + c0);
#pragma unroll
    for (int d = 0; d < 4; d++){
      acc[2*d]   += a * b2f((unsigned short)(pv[d] & 0xffffu));
      acc[2*d+1] += a * b2f((unsigned short)(pv[d] >> 16));
    }
  }

  // residual + bias, write rst into res half of comb
  unsigned short* rp = comb + n * 1024 + 512 + c0;
  u32x4 rv = *reinterpret_cast<const u32x4*>(rp);
  const f32x4* bp = reinterpret_cast<const f32x4*>(bias + c0);
  f32x4 b0 = bp[0], b1 = bp[1];
  u32x4 ov;
#pragma unroll
  for (int d = 0; d < 4; d++){
    float v0 = acc[2*d]   + b2f((unsigned short)(rv[d] & 0xffffu)) + ((d < 2) ? b0[2*d]   : b1[2*d-4]);
    float v1 = acc[2*d+1] + b2f((unsigned short)(rv[d] >> 16))     + ((d < 2) ? b0[2*d+1] : b1[2*d-3]);
    ov[d] = (unsigned int)f2b(v0) | ((unsigned int)f2b(v1) << 16);
  }
  *reinterpret_cast<u32x4*>(rp) = ov;
}

// ---- BN stats: 469 blocks x 64 rows, 16B/lane loads, LDS block-reduce ----
__global__ __launch_bounds__(256) void k_stats(const unsigned short* __restrict__ comb,
                                               float* __restrict__ gsum, float* __restrict__ gsq){
  __shared__ float lsum[256][8];
  __shared__ float lsq[256][8];
  int t = threadIdx.x, lane = t & 63, rg = t >> 6;
  int c0 = lane * 8;
  int r0 = blockIdx.x * 64;
  float s[8] = {}, q[8] = {};
  for (int r = r0 + rg; r < r0 + 64 && r < N_; r += 4){
    u32x4 pv = *reinterpret_cast<const u32x4*>(comb + r * 1024 + 512 + c0);
#pragma unroll
    for (int d = 0; d < 4; d++){
      float v0 = b2f((unsigned short)(pv[d] & 0xffffu));
      float v1 = b2f((unsigned short)(pv[d] >> 16));
      s[2*d] += v0;   q[2*d] += v0 * v0;
      s[2*d+1] += v1; q[2*d+1] += v1 * v1;
    }
  }
#pragma unroll
  for (int d = 0; d < 8; d++){ lsum[t][d] = s[d]; lsq[t][d] = q[d]; }
  __syncthreads();
  if (t < 64){
#pragma unroll
    for (int d = 0; d < 8; d++){
      float ts = lsum[t][d] + lsum[t+64][d] + lsum[t+128][d] + lsum[t+192][d];
      float tq = lsq[t][d] + lsq[t+64][d] + lsq[t+128][d] + lsq[t+192][d];
      atomicAdd(&gsum[c0 + d], ts);
      atomicAdd(&gsq[c0 + d], tq);
    }
  }
}

// ---- finalize BN affine ----
__global__ void k_bnfin(const float* __restrict__ gsum, const float* __restrict__ gsq,
                        const float* __restrict__ gamma, const float* __restrict__ beta,
                        float* __restrict__ scale, float* __restrict__ shift){
  int t = threadIdx.x;
  if (t < 512){
    float mu  = gsum[t] / (float)N_;
    float var = gsq[t] / (float)N_ - mu * mu;
    float inv = rsqrtf(var + 1e-5f);
    float sc  = gamma[t] * inv;
    scale[t] = sc;
    shift[t] = beta[t] - mu * sc;
  }
}

// ---- GEMM2 (MFMA): out = relu(BN(rst)) @ W_out + b_out, fp32 out ----
__global__ __launch_bounds__(256) void k_gemm2(const unsigned short* __restrict__ comb,
                                               const unsigned short* __restrict__ WtOut,
                                               const float* __restrict__ scale,
                                               const float* __restrict__ shift,
                                               const float* __restrict__ bout,
                                               float* __restrict__ out){
  __shared__ float sc[512], sh[512], bo[128];
  int t = threadIdx.x;
  for (int i = t; i < 512; i += 256){ sc[i] = scale[i]; sh[i] = shift[i]; }
  if (t < 128) bo[t] = bout[t];
  __syncthreads();
  int wave = t >> 6, lane = t & 63, lrow = lane & 15, quad = lane >> 4;
  int rowbase = blockIdx.x * 64 + wave * 16;
  int rr = rowbase + lrow; if (rr > N_ - 1) rr = N_ - 1;
  const unsigned short* arow = comb + rr * 1024 + 512;
  f32x4 acc[8] = {};
#pragma unroll
  for (int kk = 0; kk < 16; kk++){
    int base = kk * 32 + quad * 8;
    Frag a; a.q = *reinterpret_cast<const u32x4*>(arow + base);
#pragma unroll
    for (int i = 0; i < 8; i++){
      float x = b2f(a.us[i]);
      x = fmaf(x, sc[base + i], sh[base + i]);
      a.us[i] = f2b(fmaxf(x, 0.0f));
    }
#pragma unroll
    for (int s = 0; s < 8; s++){
      int col = s * 16 + lrow;
      Frag b; b.q = *reinterpret_cast<const u32x4*>(WtOut + col * 512 + base);
      acc[s] = __builtin_amdgcn_mfma_f32_16x16x32_bf16(a.v, b.v, acc[s], 0, 0, 0);
    }
  }
#pragma unroll
  for (int s = 0; s < 8; s++){
    int col = s * 16 + lrow;
    float bb = bo[col];
#pragma unroll
    for (int j = 0; j < 4; j++){
      int gr = rowbase + quad * 4 + j;
      if (gr < N_) out[gr * 128 + col] = acc[s][j] + bb;
    }
  }
}

extern "C" void kernel_launch(void* const* d_in, const int* in_sizes, int n_in,
                              void* d_out, int out_size, void* d_ws, size_t ws_size,
                              hipStream_t stream){
  const float* feat  = (const float*)d_in[0];
  const int*   src   = (const int*)d_in[1];
  const int*   dst   = (const int*)d_in[2];
  const float* Wfc   = (const float*)d_in[3];
  const float* al    = (const float*)d_in[4];
  const float* ar    = (const float*)d_in[5];
  const float* Wres  = (const float*)d_in[6];
  const float* bias  = (const float*)d_in[7];
  const float* gamma = (const float*)d_in[8];
  const float* beta  = (const float*)d_in[9];
  const float* Wout  = (const float*)d_in[10];
  const float* bout  = (const float*)d_in[11];
  float* out = (float*)d_out;

  char* ws = (char*)d_ws;
  unsigned short* comb   = (unsigned short*)(ws + 0);          // 61,440,000 B
  unsigned short* Wt     = (unsigned short*)(ws + 61440000);
  unsigned short* WtOut  = (unsigned short*)(ws + 61702144);
  float*          el     = (float*)(ws + 61833216);
  float*          er     = (float*)(ws + 62313216);
  float*          escore = (float*)(ws + 62793216);
  int*            offs   = (int*)(ws + 70473216);
  int*            counts = (int*)(ws + 70593280);
  int*            cursor = (int*)(ws + 70713344);
  int*            eid    = (int*)(ws + 70833408);
  float*          gsum   = (float*)(ws + 72753408);
  float*          gsq    = (float*)(ws + 72755456);
  float*          scale  = (float*)(ws + 72757504);
  float*          shift  = (float*)(ws + 72759552);

  k_initconv<<<640, 256, 0, stream>>>(Wfc, Wres, Wout, Wt, WtOut,
                                      counts, cursor, gsum, gsq);
  k_hist<<<(E_ + 255) / 256, 256, 0, stream>>>(dst, counts);
  k_scan<<<1, 1024, 0, stream>>>(counts, offs);
  dim3 g1((N_ + 63) / 64, 8);
  k_gemm1<<<g1, 256, 0, stream>>>(feat, Wt, al, ar, comb, el, er);
  k_edge<<<(E_ + 255) / 256, 256, 0, stream>>>(src, dst, el, er, escore, offs, cursor, eid);
  k_aggr<<<(N_ + 3) / 4, 256, 0, stream>>>(offs, eid, src, escore, comb, bias);
  k_stats<<<(N_ + 63) / 64, 256, 0, stream>>>(comb, gsum, gsq);
  k_bnfin<<<1, 512, 0, stream>>>(gsum, gsq, gamma, beta, scale, shift);
  k_gemm2<<<(N_ + 63) / 64, 256, 0, stream>>>(comb, WtOut, scale, shift, bout, out);
}

// Round 10
// 421.785 us; speedup vs baseline: 1.3686x; 1.1111x over previous
//
#include <hip/hip_runtime.h>

#define N_  30000
#define E_  480000

typedef short short8 __attribute__((ext_vector_type(8)));
typedef float f32x4  __attribute__((ext_vector_type(4)));
typedef unsigned int u32x4 __attribute__((ext_vector_type(4)));
union Frag { u32x4 q; short8 v; unsigned short us[8]; };

__device__ __forceinline__ float b2f(unsigned short u){
  union { unsigned int i; float f; } v; v.i = ((unsigned int)u) << 16; return v.f;
}
__device__ __forceinline__ unsigned short f2b(float f){
  union { float f; unsigned int u; } v; v.f = f;
  unsigned int u = v.u;
  return (unsigned short)((u + 0x7fffu + ((u >> 16) & 1u)) >> 16);
}

// ---- init scratch + convert/transpose weights ----
__global__ void k_initconv(const float* __restrict__ Wfc, const float* __restrict__ Wres,
                           const float* __restrict__ Wout,
                           unsigned short* __restrict__ Wt, unsigned short* __restrict__ WtOut,
                           int* __restrict__ counts, int* __restrict__ cursor){
  int gid = blockIdx.x * 256 + threadIdx.x;
  if (gid < N_){ counts[gid] = 0; cursor[gid] = 0; }
  const int total1 = 1024 * 128;
  const int total2 = 128 * 512;
  for (int i = gid; i < total1 + total2; i += gridDim.x * 256){
    if (i < total1){
      int c = i >> 7, k = i & 127;
      float v = (c < 512) ? Wfc[k * 512 + c] : Wres[k * 512 + (c - 512)];
      Wt[c * 128 + k] = f2b(v);
    } else {
      int j = i - total1;
      int n = j >> 9, k = j & 511;
      WtOut[n * 512 + k] = f2b(Wout[k * 128 + n]);
    }
  }
}

// ---- histogram of dst ----
__global__ void k_hist(const int* __restrict__ dst, int* __restrict__ counts){
  int e = blockIdx.x * 256 + threadIdx.x;
  if (e < E_) atomicAdd(&counts[dst[e]], 1);
}

// ---- exclusive scan -> offs[0..N_]: 1 block, register-serial + shuffle ----
__global__ __launch_bounds__(1024) void k_scan(const int* __restrict__ counts,
                                               int* __restrict__ offs){
  __shared__ int wsum[16];
  int t = threadIdx.x;
  int lane = t & 63, w = t >> 6;
  int base = t * 32;
  int vals[32];
  int s = 0;
#pragma unroll
  for (int j = 0; j < 32; j++){
    int idx = base + j;
    int v = (idx < N_) ? counts[idx] : 0;
    vals[j] = s;
    s += v;
  }
  int x = s;
  for (int o = 1; o < 64; o <<= 1){
    int y = __shfl_up(x, o);
    if (lane >= o) x += y;
  }
  if (lane == 63) wsum[w] = x;
  __syncthreads();
  if (t < 16){
    int y = wsum[t];
    for (int o = 1; o < 16; o <<= 1){
      int z = __shfl_up(y, o, 16);
      if (t >= o) y += z;
    }
    wsum[t] = y;
  }
  __syncthreads();
  int wbase = (w > 0) ? wsum[w - 1] : 0;
  int ex = wbase + x - s;
#pragma unroll
  for (int j = 0; j < 32; j++){
    int idx = base + j;
    if (idx <= N_) offs[idx] = ex + vals[j];
  }
}

// ---- GEMM1 (MFMA) + fused el/er epilogue ----
__global__ __launch_bounds__(256) void k_gemm1(const float* __restrict__ feat,
                                               const unsigned short* __restrict__ Wt,
                                               const float* __restrict__ al,
                                               const float* __restrict__ ar,
                                               unsigned short* __restrict__ comb,
                                               float* __restrict__ el,
                                               float* __restrict__ er){
  int tid = threadIdx.x;
  int wave = tid >> 6, lane = tid & 63;
  int lrow = lane & 15, quad = lane >> 4;
  int rowbase = blockIdx.x * 64 + wave * 16;
  int colbase = blockIdx.y * 128;
  int arow = rowbase + lrow; if (arow > N_ - 1) arow = N_ - 1;
  const float* aptr = feat + arow * 128 + quad * 8;
  f32x4 acc[8] = {};
#pragma unroll
  for (int kk = 0; kk < 4; kk++){
    const f32x4* ap = reinterpret_cast<const f32x4*>(aptr + kk * 32);
    f32x4 a0 = ap[0], a1 = ap[1];
    Frag a;
#pragma unroll
    for (int i = 0; i < 4; i++){ a.us[i] = f2b(a0[i]); a.us[4 + i] = f2b(a1[i]); }
#pragma unroll
    for (int s = 0; s < 8; s++){
      int col = colbase + s * 16 + lrow;
      Frag b; b.q = *reinterpret_cast<const u32x4*>(Wt + col * 128 + kk * 32 + quad * 8);
      acc[s] = __builtin_amdgcn_mfma_f32_16x16x32_bf16(a.v, b.v, acc[s], 0, 0, 0);
    }
  }
#pragma unroll
  for (int s = 0; s < 8; s++){
    int col = colbase + s * 16 + lrow;
#pragma unroll
    for (int j = 0; j < 4; j++){
      int gr = rowbase + quad * 4 + j;
      if (gr < N_) comb[gr * 1024 + col] = f2b(acc[s][j]);
    }
  }
  if (blockIdx.y < 4){
    int h = blockIdx.y;
    float pl[4] = {}, pr[4] = {};
#pragma unroll
    for (int s = 0; s < 8; s++){
      float av = al[h * 128 + s * 16 + lrow];
      float rv = ar[h * 128 + s * 16 + lrow];
#pragma unroll
      for (int j = 0; j < 4; j++){
        pl[j] += acc[s][j] * av;
        pr[j] += acc[s][j] * rv;
      }
    }
    for (int o = 8; o >= 1; o >>= 1){
#pragma unroll
      for (int j = 0; j < 4; j++){
        pl[j] += __shfl_down(pl[j], o, 16);
        pr[j] += __shfl_down(pr[j], o, 16);
      }
    }
    if (lrow == 0){
#pragma unroll
      for (int j = 0; j < 4; j++){
        int gr = rowbase + quad * 4 + j;
        if (gr < N_){ el[gr * 4 + h] = pl[j]; er[gr * 4 + h] = pr[j]; }
      }
    }
  }
}

// ---- per-edge score (leaky relu) + CSR scatter ----
__global__ void k_edge(const int* __restrict__ src, const int* __restrict__ dst,
                       const float* __restrict__ el, const float* __restrict__ er,
                       float* __restrict__ escore, const int* __restrict__ offs,
                       int* __restrict__ cursor, int* __restrict__ eid){
  int e = blockIdx.x * 256 + threadIdx.x;
  if (e >= E_) return;
  int s = src[e], d = dst[e];
  f32x4 a = *reinterpret_cast<const f32x4*>(el + s * 4);
  f32x4 b = *reinterpret_cast<const f32x4*>(er + d * 4);
  f32x4 v = a + b;
#pragma unroll
  for (int i = 0; i < 4; i++) v[i] = v[i] > 0.f ? v[i] : 0.2f * v[i];
  *reinterpret_cast<f32x4*>(escore + e * 4) = v;
  int p = atomicAdd(&cursor[d], 1);
  eid[offs[d] + p] = e;
}

// ---- per-dst softmax + gather: one wave per node, 4-way unrolled gather ----
__global__ __launch_bounds__(256) void k_aggr(const int* __restrict__ offs,
                                              const int* __restrict__ eid,
                                              const int* __restrict__ src,
                                              const float* __restrict__ escore,
                                              unsigned short* __restrict__ comb,
                                              const float* __restrict__ bias){
  int wave = threadIdx.x >> 6, lane = threadIdx.x & 63;
  int n = blockIdx.x * 4 + wave;
  if (n >= N_) return;
  int head = lane >> 4, sub = lane & 15;
  int off0 = offs[n], g = offs[n + 1] - off0;

  float m = -1e30f;
  for (int i = sub; i < g; i += 16)
    m = fmaxf(m, escore[eid[off0 + i] * 4 + head]);
  for (int o = 8; o >= 1; o >>= 1) m = fmaxf(m, __shfl_xor(m, o, 16));
  float ss = 0.f;
  for (int i = sub; i < g; i += 16)
    ss += __expf(escore[eid[off0 + i] * 4 + head] - m);
  for (int o = 8; o >= 1; o >>= 1) ss += __shfl_xor(ss, o, 16);
  float rd = (ss > 0.f) ? 1.0f / ss : 0.f;

  int c0 = lane * 8;
  float acc[8] = {};
  int i = 0;
  for (; i + 3 < g; i += 4){
    int ea = eid[off0 + i],     eb = eid[off0 + i + 1];
    int ec = eid[off0 + i + 2], ed = eid[off0 + i + 3];
    int sa = src[ea], sb = src[eb], sc2 = src[ec], sd = src[ed];
    float va = escore[ea * 4 + head], vb = escore[eb * 4 + head];
    float vc = escore[ec * 4 + head], vd = escore[ed * 4 + head];
    u32x4 pa = *reinterpret_cast<const u32x4*>(comb + sa * 1024 + c0);
    u32x4 pb = *reinterpret_cast<const u32x4*>(comb + sb * 1024 + c0);
    u32x4 pc = *reinterpret_cast<const u32x4*>(comb + sc2 * 1024 + c0);
    u32x4 pd = *reinterpret_cast<const u32x4*>(comb + sd * 1024 + c0);
    float aa = __expf(va - m) * rd, ab = __expf(vb - m) * rd;
    float ac2 = __expf(vc - m) * rd, ad = __expf(vd - m) * rd;
#pragma unroll
    for (int d = 0; d < 4; d++){
      acc[2*d]   += aa * b2f((unsigned short)(pa[d] & 0xffffu))
                  + ab * b2f((unsigned short)(pb[d] & 0xffffu))
                  + ac2 * b2f((unsigned short)(pc[d] & 0xffffu))
                  + ad * b2f((unsigned short)(pd[d] & 0xffffu));
      acc[2*d+1] += aa * b2f((unsigned short)(pa[d] >> 16))
                  + ab * b2f((unsigned short)(pb[d] >> 16))
                  + ac2 * b2f((unsigned short)(pc[d] >> 16))
                  + ad * b2f((unsigned short)(pd[d] >> 16));
    }
  }
  for (; i < g; i++){
    int e = eid[off0 + i];
    int sv = src[e];
    float a = __expf(escore[e * 4 + head] - m) * rd;
    u32x4 pv = *reinterpret_cast<const u32x4*>(comb + sv * 1024 + c0);
#pragma unroll
    for (int d = 0; d < 4; d++){
      acc[2*d]   += a * b2f((unsigned short)(pv[d] & 0xffffu));
      acc[2*d+1] += a * b2f((unsigned short)(pv[d] >> 16));
    }
  }

  unsigned short* rp = comb + n * 1024 + 512 + c0;
  u32x4 rv = *reinterpret_cast<const u32x4*>(rp);
  const f32x4* bp = reinterpret_cast<const f32x4*>(bias + c0);
  f32x4 b0 = bp[0], b1 = bp[1];
  u32x4 ov;
#pragma unroll
  for (int d = 0; d < 4; d++){
    float v0 = acc[2*d]   + b2f((unsigned short)(rv[d] & 0xffffu)) + ((d < 2) ? b0[2*d]   : b1[2*d-4]);
    float v1 = acc[2*d+1] + b2f((unsigned short)(rv[d] >> 16))     + ((d < 2) ? b0[2*d+1] : b1[2*d-3]);
    ov[d] = (unsigned int)f2b(v0) | ((unsigned int)f2b(v1) << 16);
  }
  *reinterpret_cast<u32x4*>(rp) = ov;
}

// ---- BN stats v3: NO atomics, NO LDS. 256 blocks x 4 waves; each wave owns a
// full 512-channel register partial (lane = 8 ch) and writes a private 2 KB row.
__global__ __launch_bounds__(256) void k_stats(const unsigned short* __restrict__ comb,
                                               float* __restrict__ psum,
                                               float* __restrict__ psq){
  int t = threadIdx.x, lane = t & 63, rg = t >> 6;
  int c0 = lane * 8;
  const int rows = 118;                    // ceil(30000/256)
  int r0 = blockIdx.x * rows;
  int r1 = r0 + rows; if (r1 > N_) r1 = N_;
  float s[8] = {}, q[8] = {};
  for (int r = r0 + rg; r < r1; r += 4){
    u32x4 pv = *reinterpret_cast<const u32x4*>(comb + r * 1024 + 512 + c0);
#pragma unroll
    for (int d = 0; d < 4; d++){
      float v0 = b2f((unsigned short)(pv[d] & 0xffffu));
      float v1 = b2f((unsigned short)(pv[d] >> 16));
      s[2*d]   += v0; q[2*d]   += v0 * v0;
      s[2*d+1] += v1; q[2*d+1] += v1 * v1;
    }
  }
  int pb = (blockIdx.x * 4 + rg) * 512 + c0;   // wave-private partial row
#pragma unroll
  for (int d = 0; d < 8; d++){ psum[pb + d] = s[d]; psq[pb + d] = q[d]; }
}

// ---- finalize BN: reduce 1024 partial rows, compute scale/shift ----
__global__ void k_bnfin(const float* __restrict__ psum, const float* __restrict__ psq,
                        const float* __restrict__ gamma, const float* __restrict__ beta,
                        float* __restrict__ scale, float* __restrict__ shift){
  int t = threadIdx.x;   // 512 threads, one channel each
  if (t >= 512) return;
  float s0 = 0.f, s1 = 0.f, s2 = 0.f, s3 = 0.f;
  float q0 = 0.f, q1 = 0.f, q2 = 0.f, q3 = 0.f;
  for (int b = 0; b < 1024; b += 4){
    s0 += psum[(b    ) * 512 + t];
    s1 += psum[(b + 1) * 512 + t];
    s2 += psum[(b + 2) * 512 + t];
    s3 += psum[(b + 3) * 512 + t];
    q0 += psq[(b    ) * 512 + t];
    q1 += psq[(b + 1) * 512 + t];
    q2 += psq[(b + 2) * 512 + t];
    q3 += psq[(b + 3) * 512 + t];
  }
  float sum = (s0 + s1) + (s2 + s3);
  float sq  = (q0 + q1) + (q2 + q3);
  float mu  = sum / (float)N_;
  float var = sq / (float)N_ - mu * mu;
  float inv = rsqrtf(var + 1e-5f);
  float sc  = gamma[t] * inv;
  scale[t] = sc;
  shift[t] = beta[t] - mu * sc;
}

// ---- GEMM2 (MFMA): out = relu(BN(rst)) @ W_out + b_out, fp32 out ----
__global__ __launch_bounds__(256) void k_gemm2(const unsigned short* __restrict__ comb,
                                               const unsigned short* __restrict__ WtOut,
                                               const float* __restrict__ scale,
                                               const float* __restrict__ shift,
                                               const float* __restrict__ bout,
                                               float* __restrict__ out){
  __shared__ float sc[512], sh[512], bo[128];
  int t = threadIdx.x;
  for (int i = t; i < 512; i += 256){ sc[i] = scale[i]; sh[i] = shift[i]; }
  if (t < 128) bo[t] = bout[t];
  __syncthreads();
  int wave = t >> 6, lane = t & 63, lrow = lane & 15, quad = lane >> 4;
  int rowbase = blockIdx.x * 64 + wave * 16;
  int rr = rowbase + lrow; if (rr > N_ - 1) rr = N_ - 1;
  const unsigned short* arow = comb + rr * 1024 + 512;
  f32x4 acc[8] = {};
#pragma unroll
  for (int kk = 0; kk < 16; kk++){
    int base = kk * 32 + quad * 8;
    Frag a; a.q = *reinterpret_cast<const u32x4*>(arow + base);
#pragma unroll
    for (int i = 0; i < 8; i++){
      float x = b2f(a.us[i]);
      x = fmaf(x, sc[base + i], sh[base + i]);
      a.us[i] = f2b(fmaxf(x, 0.0f));
    }
#pragma unroll
    for (int s = 0; s < 8; s++){
      int col = s * 16 + lrow;
      Frag b; b.q = *reinterpret_cast<const u32x4*>(WtOut + col * 512 + base);
      acc[s] = __builtin_amdgcn_mfma_f32_16x16x32_bf16(a.v, b.v, acc[s], 0, 0, 0);
    }
  }
#pragma unroll
  for (int s = 0; s < 8; s++){
    int col = s * 16 + lrow;
    float bb = bo[col];
#pragma unroll
    for (int j = 0; j < 4; j++){
      int gr = rowbase + quad * 4 + j;
      if (gr < N_) out[gr * 128 + col] = acc[s][j] + bb;
    }
  }
}

extern "C" void kernel_launch(void* const* d_in, const int* in_sizes, int n_in,
                              void* d_out, int out_size, void* d_ws, size_t ws_size,
                              hipStream_t stream){
  const float* feat  = (const float*)d_in[0];
  const int*   src   = (const int*)d_in[1];
  const int*   dst   = (const int*)d_in[2];
  const float* Wfc   = (const float*)d_in[3];
  const float* al    = (const float*)d_in[4];
  const float* ar    = (const float*)d_in[5];
  const float* Wres  = (const float*)d_in[6];
  const float* bias  = (const float*)d_in[7];
  const float* gamma = (const float*)d_in[8];
  const float* beta  = (const float*)d_in[9];
  const float* Wout  = (const float*)d_in[10];
  const float* bout  = (const float*)d_in[11];
  float* out = (float*)d_out;

  char* ws = (char*)d_ws;
  unsigned short* comb   = (unsigned short*)(ws + 0);          // 61,440,000 B
  unsigned short* Wt     = (unsigned short*)(ws + 61440000);
  unsigned short* WtOut  = (unsigned short*)(ws + 61702144);
  float*          el     = (float*)(ws + 61833216);
  float*          er     = (float*)(ws + 62313216);
  float*          escore = (float*)(ws + 62793216);
  int*            offs   = (int*)(ws + 70473216);
  int*            counts = (int*)(ws + 70593280);
  int*            cursor = (int*)(ws + 70713344);
  int*            eid    = (int*)(ws + 70833408);
  float*          psum   = (float*)(ws + 72753408);            // 1024*512*4 = 2,097,152
  float*          psq    = (float*)(ws + 74850560);            // 2,097,152
  float*          scale  = (float*)(ws + 76947712);            // 2,048
  float*          shift  = (float*)(ws + 76949760);            // 2,048

  k_initconv<<<640, 256, 0, stream>>>(Wfc, Wres, Wout, Wt, WtOut, counts, cursor);
  k_hist<<<(E_ + 255) / 256, 256, 0, stream>>>(dst, counts);
  k_scan<<<1, 1024, 0, stream>>>(counts, offs);
  dim3 g1((N_ + 63) / 64, 8);
  k_gemm1<<<g1, 256, 0, stream>>>(feat, Wt, al, ar, comb, el, er);
  k_edge<<<(E_ + 255) / 256, 256, 0, stream>>>(src, dst, el, er, escore, offs, cursor, eid);
  k_aggr<<<(N_ + 3) / 4, 256, 0, stream>>>(offs, eid, src, escore, comb, bias);
  k_stats<<<256, 256, 0, stream>>>(comb, psum, psq);
  k_bnfin<<<1, 512, 0, stream>>>(psum, psq, gamma, beta, scale, shift);
  k_gemm2<<<(N_ + 63) / 64, 256, 0, stream>>>(comb, WtOut, scale, shift, bout, out);
}

// Round 11
// 411.125 us; speedup vs baseline: 1.4041x; 1.0259x over previous
//
#include <hip/hip_runtime.h>

#define N_  30000
#define E_  480000

typedef short short8 __attribute__((ext_vector_type(8)));
typedef float f32x4  __attribute__((ext_vector_type(4)));
typedef unsigned int u32x4 __attribute__((ext_vector_type(4)));
union Frag { u32x4 q; short8 v; unsigned short us[8]; };

__device__ __forceinline__ float b2f(unsigned short u){
  union { unsigned int i; float f; } v; v.i = ((unsigned int)u) << 16; return v.f;
}
__device__ __forceinline__ unsigned short f2b(float f){
  union { float f; unsigned int u; } v; v.f = f;
  unsigned int u = v.u;
  return (unsigned short)((u + 0x7fffu + ((u >> 16) & 1u)) >> 16);
}

// ---- init scratch + convert weights AND feat to bf16 ----
__global__ void k_initconv(const float* __restrict__ Wfc, const float* __restrict__ Wres,
                           const float* __restrict__ Wout, const float* __restrict__ feat,
                           unsigned short* __restrict__ Wt, unsigned short* __restrict__ WtOut,
                           unsigned short* __restrict__ featb,
                           int* __restrict__ counts, int* __restrict__ cursor){
  int gid = blockIdx.x * 256 + threadIdx.x;
  int stride = gridDim.x * 256;
  if (gid < N_){ counts[gid] = 0; cursor[gid] = 0; }
  const int total1 = 1024 * 128;
  const int total2 = 128 * 512;
  for (int i = gid; i < total1 + total2; i += stride){
    if (i < total1){
      int c = i >> 7, k = i & 127;
      float v = (c < 512) ? Wfc[k * 512 + c] : Wres[k * 512 + (c - 512)];
      Wt[c * 128 + k] = f2b(v);
    } else {
      int j = i - total1;
      int n = j >> 9, k = j & 511;
      WtOut[n * 512 + k] = f2b(Wout[k * 128 + n]);
    }
  }
  for (int i = gid; i < N_ * 128; i += stride)
    featb[i] = f2b(feat[i]);
}

// ---- histogram of dst ----
__global__ void k_hist(const int* __restrict__ dst, int* __restrict__ counts){
  int e = blockIdx.x * 256 + threadIdx.x;
  if (e < E_) atomicAdd(&counts[dst[e]], 1);
}

// ---- exclusive scan -> offs[0..N_]: 1 block, register-serial + shuffle ----
__global__ __launch_bounds__(1024) void k_scan(const int* __restrict__ counts,
                                               int* __restrict__ offs){
  __shared__ int wsum[16];
  int t = threadIdx.x;
  int lane = t & 63, w = t >> 6;
  int base = t * 32;
  int vals[32];
  int s = 0;
#pragma unroll
  for (int j = 0; j < 32; j++){
    int idx = base + j;
    int v = (idx < N_) ? counts[idx] : 0;
    vals[j] = s;
    s += v;
  }
  int x = s;
  for (int o = 1; o < 64; o <<= 1){
    int y = __shfl_up(x, o);
    if (lane >= o) x += y;
  }
  if (lane == 63) wsum[w] = x;
  __syncthreads();
  if (t < 16){
    int y = wsum[t];
    for (int o = 1; o < 16; o <<= 1){
      int z = __shfl_up(y, o, 16);
      if (t >= o) y += z;
    }
    wsum[t] = y;
  }
  __syncthreads();
  int wbase = (w > 0) ? wsum[w - 1] : 0;
  int ex = wbase + x - s;
#pragma unroll
  for (int j = 0; j < 32; j++){
    int idx = base + j;
    if (idx <= N_) offs[idx] = ex + vals[j];
  }
}

// ---- GEMM1 (MFMA): bf16 feat, 64 rows x 256 cols/block, fused el/er ----
// grid (469, 4). by<2: block covers heads 2by, 2by+1 -> compute el/er here.
__global__ __launch_bounds__(256) void k_gemm1(const unsigned short* __restrict__ featb,
                                               const unsigned short* __restrict__ Wt,
                                               const float* __restrict__ al,
                                               const float* __restrict__ ar,
                                               unsigned short* __restrict__ comb,
                                               float* __restrict__ el,
                                               float* __restrict__ er){
  int tid = threadIdx.x;
  int wave = tid >> 6, lane = tid & 63;
  int lrow = lane & 15, quad = lane >> 4;
  int rowbase = blockIdx.x * 64 + wave * 16;
  int colbase = blockIdx.y * 256;
  int arow = rowbase + lrow; if (arow > N_ - 1) arow = N_ - 1;
  const unsigned short* aptr = featb + arow * 128 + quad * 8;
  f32x4 acc[16] = {};
#pragma unroll
  for (int kk = 0; kk < 4; kk++){
    Frag a; a.q = *reinterpret_cast<const u32x4*>(aptr + kk * 32);
#pragma unroll
    for (int s = 0; s < 16; s++){
      int col = colbase + s * 16 + lrow;
      Frag b; b.q = *reinterpret_cast<const u32x4*>(Wt + col * 128 + kk * 32 + quad * 8);
      acc[s] = __builtin_amdgcn_mfma_f32_16x16x32_bf16(a.v, b.v, acc[s], 0, 0, 0);
    }
  }
#pragma unroll
  for (int s = 0; s < 16; s++){
    int col = colbase + s * 16 + lrow;
#pragma unroll
    for (int j = 0; j < 4; j++){
      int gr = rowbase + quad * 4 + j;   // C/D: col=lane&15, row=quad*4+reg
      if (gr < N_) comb[gr * 1024 + col] = f2b(acc[s][j]);
    }
  }
  if (blockIdx.y < 2){
    int h0 = blockIdx.y * 2;
    float pl[2][4] = {}, pr[2][4] = {};
#pragma unroll
    for (int s = 0; s < 16; s++){
      int hh = s >> 3;
      int d = (s & 7) * 16 + lrow;
      float av = al[(h0 + hh) * 128 + d];
      float rv = ar[(h0 + hh) * 128 + d];
#pragma unroll
      for (int j = 0; j < 4; j++){
        pl[hh][j] += acc[s][j] * av;
        pr[hh][j] += acc[s][j] * rv;
      }
    }
    for (int o = 8; o >= 1; o >>= 1){
#pragma unroll
      for (int hh = 0; hh < 2; hh++)
#pragma unroll
        for (int j = 0; j < 4; j++){
          pl[hh][j] += __shfl_down(pl[hh][j], o, 16);
          pr[hh][j] += __shfl_down(pr[hh][j], o, 16);
        }
    }
    if (lrow == 0){
#pragma unroll
      for (int j = 0; j < 4; j++){
        int gr = rowbase + quad * 4 + j;
        if (gr < N_){
#pragma unroll
          for (int hh = 0; hh < 2; hh++){
            el[gr * 4 + h0 + hh] = pl[hh][j];
            er[gr * 4 + h0 + hh] = pr[hh][j];
          }
        }
      }
    }
  }
}

// ---- per-edge score (leaky relu) + CSR scatter ----
__global__ void k_edge(const int* __restrict__ src, const int* __restrict__ dst,
                       const float* __restrict__ el, const float* __restrict__ er,
                       float* __restrict__ escore, const int* __restrict__ offs,
                       int* __restrict__ cursor, int* __restrict__ eid){
  int e = blockIdx.x * 256 + threadIdx.x;
  if (e >= E_) return;
  int s = src[e], d = dst[e];
  f32x4 a = *reinterpret_cast<const f32x4*>(el + s * 4);
  f32x4 b = *reinterpret_cast<const f32x4*>(er + d * 4);
  f32x4 v = a + b;
#pragma unroll
  for (int i = 0; i < 4; i++) v[i] = v[i] > 0.f ? v[i] : 0.2f * v[i];
  *reinterpret_cast<f32x4*>(escore + e * 4) = v;
  int p = atomicAdd(&cursor[d], 1);
  eid[offs[d] + p] = e;
}

// ---- per-dst softmax + gather: one wave per node, 8-way unrolled gather ----
__global__ __launch_bounds__(256) void k_aggr(const int* __restrict__ offs,
                                              const int* __restrict__ eid,
                                              const int* __restrict__ src,
                                              const float* __restrict__ escore,
                                              unsigned short* __restrict__ comb,
                                              const float* __restrict__ bias){
  int wave = threadIdx.x >> 6, lane = threadIdx.x & 63;
  int n = blockIdx.x * 4 + wave;
  if (n >= N_) return;
  int head = lane >> 4, sub = lane & 15;
  int off0 = offs[n], g = offs[n + 1] - off0;

  float m = -1e30f;
  for (int i = sub; i < g; i += 16)
    m = fmaxf(m, escore[eid[off0 + i] * 4 + head]);
  for (int o = 8; o >= 1; o >>= 1) m = fmaxf(m, __shfl_xor(m, o, 16));
  float ss = 0.f;
  for (int i = sub; i < g; i += 16)
    ss += __expf(escore[eid[off0 + i] * 4 + head] - m);
  for (int o = 8; o >= 1; o >>= 1) ss += __shfl_xor(ss, o, 16);
  float rd = (ss > 0.f) ? 1.0f / ss : 0.f;

  int c0 = lane * 8;
  float acc[8] = {};
  int i = 0;
  for (; i + 7 < g; i += 8){
    int e8[8], s8[8];
    float v8[8];
    u32x4 p8[8];
#pragma unroll
    for (int u = 0; u < 8; u++) e8[u] = eid[off0 + i + u];
#pragma unroll
    for (int u = 0; u < 8; u++) s8[u] = src[e8[u]];
#pragma unroll
    for (int u = 0; u < 8; u++) v8[u] = escore[e8[u] * 4 + head];
#pragma unroll
    for (int u = 0; u < 8; u++)
      p8[u] = *reinterpret_cast<const u32x4*>(comb + s8[u] * 1024 + c0);
#pragma unroll
    for (int u = 0; u < 8; u++){
      float a = __expf(v8[u] - m) * rd;
#pragma unroll
      for (int d = 0; d < 4; d++){
        acc[2*d]   += a * b2f((unsigned short)(p8[u][d] & 0xffffu));
        acc[2*d+1] += a * b2f((unsigned short)(p8[u][d] >> 16));
      }
    }
  }
  for (; i < g; i++){
    int e = eid[off0 + i];
    int sv = src[e];
    float a = __expf(escore[e * 4 + head] - m) * rd;
    u32x4 pv = *reinterpret_cast<const u32x4*>(comb + sv * 1024 + c0);
#pragma unroll
    for (int d = 0; d < 4; d++){
      acc[2*d]   += a * b2f((unsigned short)(pv[d] & 0xffffu));
      acc[2*d+1] += a * b2f((unsigned short)(pv[d] >> 16));
    }
  }

  unsigned short* rp = comb + n * 1024 + 512 + c0;
  u32x4 rv = *reinterpret_cast<const u32x4*>(rp);
  const f32x4* bp = reinterpret_cast<const f32x4*>(bias + c0);
  f32x4 b0 = bp[0], b1 = bp[1];
  u32x4 ov;
#pragma unroll
  for (int d = 0; d < 4; d++){
    float v0 = acc[2*d]   + b2f((unsigned short)(rv[d] & 0xffffu)) + ((d < 2) ? b0[2*d]   : b1[2*d-4]);
    float v1 = acc[2*d+1] + b2f((unsigned short)(rv[d] >> 16))     + ((d < 2) ? b0[2*d+1] : b1[2*d-3]);
    ov[d] = (unsigned int)f2b(v0) | ((unsigned int)f2b(v1) << 16);
  }
  *reinterpret_cast<u32x4*>(rp) = ov;
}

// ---- BN stats: 256 blocks, wave-register partials + LDS block-reduce -> 256 rows
__global__ __launch_bounds__(256) void k_stats(const unsigned short* __restrict__ comb,
                                               float* __restrict__ psum,
                                               float* __restrict__ psq){
  __shared__ float lsum[4][512];
  __shared__ float lsq[4][512];
  int t = threadIdx.x, lane = t & 63, rg = t >> 6;
  int c0 = lane * 8;
  const int rows = 118;                    // ceil(30000/256)
  int r0 = blockIdx.x * rows;
  int r1 = r0 + rows; if (r1 > N_) r1 = N_;
  float s[8] = {}, q[8] = {};
  for (int r = r0 + rg; r < r1; r += 4){
    u32x4 pv = *reinterpret_cast<const u32x4*>(comb + r * 1024 + 512 + c0);
#pragma unroll
    for (int d = 0; d < 4; d++){
      float v0 = b2f((unsigned short)(pv[d] & 0xffffu));
      float v1 = b2f((unsigned short)(pv[d] >> 16));
      s[2*d]   += v0; q[2*d]   += v0 * v0;
      s[2*d+1] += v1; q[2*d+1] += v1 * v1;
    }
  }
#pragma unroll
  for (int d = 0; d < 8; d++){ lsum[rg][c0 + d] = s[d]; lsq[rg][c0 + d] = q[d]; }
  __syncthreads();
  // 256 threads reduce 4 wave-partials; thread t handles channels t and t+256
#pragma unroll
  for (int half = 0; half < 2; half++){
    int ch = t + half * 256;
    float a = lsum[0][ch] + lsum[1][ch] + lsum[2][ch] + lsum[3][ch];
    float b = lsq[0][ch] + lsq[1][ch] + lsq[2][ch] + lsq[3][ch];
    psum[blockIdx.x * 512 + ch] = a;
    psq[blockIdx.x * 512 + ch] = b;
  }
}

// ---- finalize BN: 4 blocks x 128 ch, reduce 256 partial rows ----
__global__ __launch_bounds__(128) void k_bnfin(const float* __restrict__ psum,
                                               const float* __restrict__ psq,
                                               const float* __restrict__ gamma,
                                               const float* __restrict__ beta,
                                               float* __restrict__ scale,
                                               float* __restrict__ shift){
  int ch = blockIdx.x * 128 + threadIdx.x;
  float s0 = 0.f, s1 = 0.f, s2 = 0.f, s3 = 0.f;
  float q0 = 0.f, q1 = 0.f, q2 = 0.f, q3 = 0.f;
  for (int b = 0; b < 256; b += 4){
    s0 += psum[(b    ) * 512 + ch];
    s1 += psum[(b + 1) * 512 + ch];
    s2 += psum[(b + 2) * 512 + ch];
    s3 += psum[(b + 3) * 512 + ch];
    q0 += psq[(b    ) * 512 + ch];
    q1 += psq[(b + 1) * 512 + ch];
    q2 += psq[(b + 2) * 512 + ch];
    q3 += psq[(b + 3) * 512 + ch];
  }
  float sum = (s0 + s1) + (s2 + s3);
  float sq  = (q0 + q1) + (q2 + q3);
  float mu  = sum / (float)N_;
  float var = sq / (float)N_ - mu * mu;
  float inv = rsqrtf(var + 1e-5f);
  float sc  = gamma[ch] * inv;
  scale[ch] = sc;
  shift[ch] = beta[ch] - mu * sc;
}

// ---- GEMM2 (MFMA): out = relu(BN(rst)) @ W_out + b_out, fp32 out ----
__global__ __launch_bounds__(256) void k_gemm2(const unsigned short* __restrict__ comb,
                                               const unsigned short* __restrict__ WtOut,
                                               const float* __restrict__ scale,
                                               const float* __restrict__ shift,
                                               const float* __restrict__ bout,
                                               float* __restrict__ out){
  __shared__ float sc[512], sh[512], bo[128];
  int t = threadIdx.x;
  for (int i = t; i < 512; i += 256){ sc[i] = scale[i]; sh[i] = shift[i]; }
  if (t < 128) bo[t] = bout[t];
  __syncthreads();
  int wave = t >> 6, lane = t & 63, lrow = lane & 15, quad = lane >> 4;
  int rowbase = blockIdx.x * 64 + wave * 16;
  int rr = rowbase + lrow; if (rr > N_ - 1) rr = N_ - 1;
  const unsigned short* arow = comb + rr * 1024 + 512;
  f32x4 acc[8] = {};
#pragma unroll
  for (int kk = 0; kk < 16; kk++){
    int base = kk * 32 + quad * 8;
    Frag a; a.q = *reinterpret_cast<const u32x4*>(arow + base);
#pragma unroll
    for (int i = 0; i < 8; i++){
      float x = b2f(a.us[i]);
      x = fmaf(x, sc[base + i], sh[base + i]);
      a.us[i] = f2b(fmaxf(x, 0.0f));
    }
#pragma unroll
    for (int s = 0; s < 8; s++){
      int col = s * 16 + lrow;
      Frag b; b.q = *reinterpret_cast<const u32x4*>(WtOut + col * 512 + base);
      acc[s] = __builtin_amdgcn_mfma_f32_16x16x32_bf16(a.v, b.v, acc[s], 0, 0, 0);
    }
  }
#pragma unroll
  for (int s = 0; s < 8; s++){
    int col = s * 16 + lrow;
    float bb = bo[col];
#pragma unroll
    for (int j = 0; j < 4; j++){
      int gr = rowbase + quad * 4 + j;
      if (gr < N_) out[gr * 128 + col] = acc[s][j] + bb;
    }
  }
}

extern "C" void kernel_launch(void* const* d_in, const int* in_sizes, int n_in,
                              void* d_out, int out_size, void* d_ws, size_t ws_size,
                              hipStream_t stream){
  const float* feat  = (const float*)d_in[0];
  const int*   src   = (const int*)d_in[1];
  const int*   dst   = (const int*)d_in[2];
  const float* Wfc   = (const float*)d_in[3];
  const float* al    = (const float*)d_in[4];
  const float* ar    = (const float*)d_in[5];
  const float* Wres  = (const float*)d_in[6];
  const float* bias  = (const float*)d_in[7];
  const float* gamma = (const float*)d_in[8];
  const float* beta  = (const float*)d_in[9];
  const float* Wout  = (const float*)d_in[10];
  const float* bout  = (const float*)d_in[11];
  float* out = (float*)d_out;

  char* ws = (char*)d_ws;
  unsigned short* comb   = (unsigned short*)(ws + 0);          // 61,440,000
  unsigned short* Wt     = (unsigned short*)(ws + 61440000);   //    262,144
  unsigned short* WtOut  = (unsigned short*)(ws + 61702144);   //    131,072
  float*          el     = (float*)(ws + 61833216);            //    480,000
  float*          er     = (float*)(ws + 62313216);            //    480,000
  float*          escore = (float*)(ws + 62793216);            //  7,680,000
  int*            offs   = (int*)(ws + 70473216);              //    120,064
  int*            counts = (int*)(ws + 70593280);              //    120,064
  int*            cursor = (int*)(ws + 70713344);              //    120,064
  int*            eid    = (int*)(ws + 70833408);              //  1,920,000
  float*          psum   = (float*)(ws + 72753408);            //    524,288
  float*          psq    = (float*)(ws + 73277696);            //    524,288
  float*          scale  = (float*)(ws + 73801984);            //      2,048
  float*          shift  = (float*)(ws + 73804032);            //      2,048
  unsigned short* featb  = (unsigned short*)(ws + 73806080);   //  7,680,000

  k_initconv<<<640, 256, 0, stream>>>(Wfc, Wres, Wout, feat, Wt, WtOut, featb,
                                      counts, cursor);
  k_hist<<<(E_ + 255) / 256, 256, 0, stream>>>(dst, counts);
  k_scan<<<1, 1024, 0, stream>>>(counts, offs);
  dim3 g1((N_ + 63) / 64, 4);
  k_gemm1<<<g1, 256, 0, stream>>>(featb, Wt, al, ar, comb, el, er);
  k_edge<<<(E_ + 255) / 256, 256, 0, stream>>>(src, dst, el, er, escore, offs, cursor, eid);
  k_aggr<<<(N_ + 3) / 4, 256, 0, stream>>>(offs, eid, src, escore, comb, bias);
  k_stats<<<256, 256, 0, stream>>>(comb, psum, psq);
  k_bnfin<<<4, 128, 0, stream>>>(psum, psq, gamma, beta, scale, shift);
  k_gemm2<<<(N_ + 63) / 64, 256, 0, stream>>>(comb, WtOut, scale, shift, bout, out);
}

// Round 12
// 401.749 us; speedup vs baseline: 1.4369x; 1.0233x over previous
//
#include <hip/hip_runtime.h>

#define N_  30000
#define E_  480000

typedef short short8 __attribute__((ext_vector_type(8)));
typedef float f32x4  __attribute__((ext_vector_type(4)));
typedef unsigned int u32x4 __attribute__((ext_vector_type(4)));
typedef unsigned int u32x2 __attribute__((ext_vector_type(2)));
union Frag { u32x4 q; short8 v; unsigned short us[8]; };

__device__ __forceinline__ float b2f(unsigned short u){
  union { unsigned int i; float f; } v; v.i = ((unsigned int)u) << 16; return v.f;
}
__device__ __forceinline__ unsigned short f2b(float f){
  union { float f; unsigned int u; } v; v.f = f;
  unsigned int u = v.u;
  return (unsigned short)((u + 0x7fffu + ((u >> 16) & 1u)) >> 16);
}

// ---- init scratch + convert weights AND feat to bf16 ----
__global__ void k_initconv(const float* __restrict__ Wfc, const float* __restrict__ Wres,
                           const float* __restrict__ Wout, const float* __restrict__ feat,
                           unsigned short* __restrict__ Wt, unsigned short* __restrict__ WtOut,
                           unsigned short* __restrict__ featb,
                           int* __restrict__ counts, int* __restrict__ cursor){
  int gid = blockIdx.x * 256 + threadIdx.x;
  int stride = gridDim.x * 256;
  if (gid < N_){ counts[gid] = 0; cursor[gid] = 0; }
  const int total1 = 1024 * 128;
  const int total2 = 128 * 512;
  for (int i = gid; i < total1 + total2; i += stride){
    if (i < total1){
      int c = i >> 7, k = i & 127;
      float v = (c < 512) ? Wfc[k * 512 + c] : Wres[k * 512 + (c - 512)];
      Wt[c * 128 + k] = f2b(v);
    } else {
      int j = i - total1;
      int n = j >> 9, k = j & 511;
      WtOut[n * 512 + k] = f2b(Wout[k * 128 + n]);
    }
  }
  for (int i = gid; i < N_ * 128; i += stride)
    featb[i] = f2b(feat[i]);
}

// ---- histogram of dst ----
__global__ void k_hist(const int* __restrict__ dst, int* __restrict__ counts){
  int e = blockIdx.x * 256 + threadIdx.x;
  if (e < E_) atomicAdd(&counts[dst[e]], 1);
}

// ---- exclusive scan -> offs[0..N_]: 1 block, register-serial + shuffle ----
__global__ __launch_bounds__(1024) void k_scan(const int* __restrict__ counts,
                                               int* __restrict__ offs){
  __shared__ int wsum[16];
  int t = threadIdx.x;
  int lane = t & 63, w = t >> 6;
  int base = t * 32;
  int vals[32];
  int s = 0;
#pragma unroll
  for (int j = 0; j < 32; j++){
    int idx = base + j;
    int v = (idx < N_) ? counts[idx] : 0;
    vals[j] = s;
    s += v;
  }
  int x = s;
  for (int o = 1; o < 64; o <<= 1){
    int y = __shfl_up(x, o);
    if (lane >= o) x += y;
  }
  if (lane == 63) wsum[w] = x;
  __syncthreads();
  if (t < 16){
    int y = wsum[t];
    for (int o = 1; o < 16; o <<= 1){
      int z = __shfl_up(y, o, 16);
      if (t >= o) y += z;
    }
    wsum[t] = y;
  }
  __syncthreads();
  int wbase = (w > 0) ? wsum[w - 1] : 0;
  int ex = wbase + x - s;
#pragma unroll
  for (int j = 0; j < 32; j++){
    int idx = base + j;
    if (idx <= N_) offs[idx] = ex + vals[j];
  }
}

// ---- GEMM1 (MFMA): bf16 feat, 64 rows x 256 cols/block, fused el/er ----
__global__ __launch_bounds__(256) void k_gemm1(const unsigned short* __restrict__ featb,
                                               const unsigned short* __restrict__ Wt,
                                               const float* __restrict__ al,
                                               const float* __restrict__ ar,
                                               unsigned short* __restrict__ comb,
                                               float* __restrict__ el,
                                               float* __restrict__ er){
  int tid = threadIdx.x;
  int wave = tid >> 6, lane = tid & 63;
  int lrow = lane & 15, quad = lane >> 4;
  int rowbase = blockIdx.x * 64 + wave * 16;
  int colbase = blockIdx.y * 256;
  int arow = rowbase + lrow; if (arow > N_ - 1) arow = N_ - 1;
  const unsigned short* aptr = featb + arow * 128 + quad * 8;
  f32x4 acc[16] = {};
#pragma unroll
  for (int kk = 0; kk < 4; kk++){
    Frag a; a.q = *reinterpret_cast<const u32x4*>(aptr + kk * 32);
#pragma unroll
    for (int s = 0; s < 16; s++){
      int col = colbase + s * 16 + lrow;
      Frag b; b.q = *reinterpret_cast<const u32x4*>(Wt + col * 128 + kk * 32 + quad * 8);
      acc[s] = __builtin_amdgcn_mfma_f32_16x16x32_bf16(a.v, b.v, acc[s], 0, 0, 0);
    }
  }
#pragma unroll
  for (int s = 0; s < 16; s++){
    int col = colbase + s * 16 + lrow;
#pragma unroll
    for (int j = 0; j < 4; j++){
      int gr = rowbase + quad * 4 + j;
      if (gr < N_) comb[gr * 1024 + col] = f2b(acc[s][j]);
    }
  }
  if (blockIdx.y < 2){
    int h0 = blockIdx.y * 2;
    float pl[2][4] = {}, pr[2][4] = {};
#pragma unroll
    for (int s = 0; s < 16; s++){
      int hh = s >> 3;
      int d = (s & 7) * 16 + lrow;
      float av = al[(h0 + hh) * 128 + d];
      float rv = ar[(h0 + hh) * 128 + d];
#pragma unroll
      for (int j = 0; j < 4; j++){
        pl[hh][j] += acc[s][j] * av;
        pr[hh][j] += acc[s][j] * rv;
      }
    }
    for (int o = 8; o >= 1; o >>= 1){
#pragma unroll
      for (int hh = 0; hh < 2; hh++)
#pragma unroll
        for (int j = 0; j < 4; j++){
          pl[hh][j] += __shfl_down(pl[hh][j], o, 16);
          pr[hh][j] += __shfl_down(pr[hh][j], o, 16);
        }
    }
    if (lrow == 0){
#pragma unroll
      for (int j = 0; j < 4; j++){
        int gr = rowbase + quad * 4 + j;
        if (gr < N_){
#pragma unroll
          for (int hh = 0; hh < 2; hh++){
            el[gr * 4 + h0 + hh] = pl[hh][j];
            er[gr * 4 + h0 + hh] = pr[hh][j];
          }
        }
      }
    }
  }
}

// ---- per-edge score (leaky relu) + CSR scatter ----
__global__ void k_edge(const int* __restrict__ src, const int* __restrict__ dst,
                       const float* __restrict__ el, const float* __restrict__ er,
                       float* __restrict__ escore, const int* __restrict__ offs,
                       int* __restrict__ cursor, int* __restrict__ eid){
  int e = blockIdx.x * 256 + threadIdx.x;
  if (e >= E_) return;
  int s = src[e], d = dst[e];
  f32x4 a = *reinterpret_cast<const f32x4*>(el + s * 4);
  f32x4 b = *reinterpret_cast<const f32x4*>(er + d * 4);
  f32x4 v = a + b;
#pragma unroll
  for (int i = 0; i < 4; i++) v[i] = v[i] > 0.f ? v[i] : 0.2f * v[i];
  *reinterpret_cast<f32x4*>(escore + e * 4) = v;
  int p = atomicAdd(&cursor[d], 1);
  eid[offs[d] + p] = e;
}

// ---- per-dst softmax + gather: TWO waves per node (256 ch each), 4-way unroll
// lane owns 4 channels (8 B loads); 32-lane groups share one head.
__global__ __launch_bounds__(256) void k_aggr(const int* __restrict__ offs,
                                              const int* __restrict__ eid,
                                              const int* __restrict__ src,
                                              const float* __restrict__ escore,
                                              unsigned short* __restrict__ comb,
                                              const float* __restrict__ bias){
  int wave = threadIdx.x >> 6, lane = threadIdx.x & 63;
  int n = blockIdx.x * 2 + (wave >> 1);
  if (n >= N_) return;
  int half = wave & 1;
  int c0 = half * 256 + lane * 4;          // 4 channels per lane
  int head = c0 >> 7;                      // 32-lane group shares a head
  int sub = lane & 31;
  int off0 = offs[n], g = offs[n + 1] - off0;

  // per-head max and sum-of-exp over 32-lane group
  float m = -1e30f;
  for (int i = sub; i < g; i += 32)
    m = fmaxf(m, escore[eid[off0 + i] * 4 + head]);
  for (int o = 16; o >= 1; o >>= 1) m = fmaxf(m, __shfl_xor(m, o, 32));
  float ss = 0.f;
  for (int i = sub; i < g; i += 32)
    ss += __expf(escore[eid[off0 + i] * 4 + head] - m);
  for (int o = 16; o >= 1; o >>= 1) ss += __shfl_xor(ss, o, 32);
  float rd = (ss > 0.f) ? 1.0f / ss : 0.f;

  // weighted gather: 4 independent chains, 8 B/lane
  float acc[4] = {};
  int i = 0;
  for (; i + 3 < g; i += 4){
    int ea = eid[off0 + i],     eb = eid[off0 + i + 1];
    int ec = eid[off0 + i + 2], ed = eid[off0 + i + 3];
    int sa = src[ea], sb = src[eb], sc2 = src[ec], sd = src[ed];
    float va = escore[ea * 4 + head], vb = escore[eb * 4 + head];
    float vc = escore[ec * 4 + head], vd = escore[ed * 4 + head];
    u32x2 pa = *reinterpret_cast<const u32x2*>(comb + sa * 1024 + c0);
    u32x2 pb = *reinterpret_cast<const u32x2*>(comb + sb * 1024 + c0);
    u32x2 pc = *reinterpret_cast<const u32x2*>(comb + sc2 * 1024 + c0);
    u32x2 pd = *reinterpret_cast<const u32x2*>(comb + sd * 1024 + c0);
    float aa = __expf(va - m) * rd, ab = __expf(vb - m) * rd;
    float ac2 = __expf(vc - m) * rd, ad = __expf(vd - m) * rd;
#pragma unroll
    for (int d = 0; d < 2; d++){
      acc[2*d]   += aa * b2f((unsigned short)(pa[d] & 0xffffu))
                  + ab * b2f((unsigned short)(pb[d] & 0xffffu))
                  + ac2 * b2f((unsigned short)(pc[d] & 0xffffu))
                  + ad * b2f((unsigned short)(pd[d] & 0xffffu));
      acc[2*d+1] += aa * b2f((unsigned short)(pa[d] >> 16))
                  + ab * b2f((unsigned short)(pb[d] >> 16))
                  + ac2 * b2f((unsigned short)(pc[d] >> 16))
                  + ad * b2f((unsigned short)(pd[d] >> 16));
    }
  }
  for (; i < g; i++){
    int e = eid[off0 + i];
    int sv = src[e];
    float a = __expf(escore[e * 4 + head] - m) * rd;
    u32x2 pv = *reinterpret_cast<const u32x2*>(comb + sv * 1024 + c0);
#pragma unroll
    for (int d = 0; d < 2; d++){
      acc[2*d]   += a * b2f((unsigned short)(pv[d] & 0xffffu));
      acc[2*d+1] += a * b2f((unsigned short)(pv[d] >> 16));
    }
  }

  // residual + bias, write rst (4 ch = 8 B)
  unsigned short* rp = comb + n * 1024 + 512 + c0;
  u32x2 rv = *reinterpret_cast<const u32x2*>(rp);
  f32x4 bb = *reinterpret_cast<const f32x4*>(bias + c0);
  u32x2 ov;
#pragma unroll
  for (int d = 0; d < 2; d++){
    float v0 = acc[2*d]   + b2f((unsigned short)(rv[d] & 0xffffu)) + bb[2*d];
    float v1 = acc[2*d+1] + b2f((unsigned short)(rv[d] >> 16))     + bb[2*d+1];
    ov[d] = (unsigned int)f2b(v0) | ((unsigned int)f2b(v1) << 16);
  }
  *reinterpret_cast<u32x2*>(rp) = ov;
}

// ---- BN stats: 256 blocks, wave-register partials + LDS block-reduce ----
__global__ __launch_bounds__(256) void k_stats(const unsigned short* __restrict__ comb,
                                               float* __restrict__ psum,
                                               float* __restrict__ psq){
  __shared__ float lsum[4][512];
  __shared__ float lsq[4][512];
  int t = threadIdx.x, lane = t & 63, rg = t >> 6;
  int c0 = lane * 8;
  const int rows = 118;
  int r0 = blockIdx.x * rows;
  int r1 = r0 + rows; if (r1 > N_) r1 = N_;
  float s[8] = {}, q[8] = {};
  for (int r = r0 + rg; r < r1; r += 4){
    u32x4 pv = *reinterpret_cast<const u32x4*>(comb + r * 1024 + 512 + c0);
#pragma unroll
    for (int d = 0; d < 4; d++){
      float v0 = b2f((unsigned short)(pv[d] & 0xffffu));
      float v1 = b2f((unsigned short)(pv[d] >> 16));
      s[2*d]   += v0; q[2*d]   += v0 * v0;
      s[2*d+1] += v1; q[2*d+1] += v1 * v1;
    }
  }
#pragma unroll
  for (int d = 0; d < 8; d++){ lsum[rg][c0 + d] = s[d]; lsq[rg][c0 + d] = q[d]; }
  __syncthreads();
#pragma unroll
  for (int half = 0; half < 2; half++){
    int ch = t + half * 256;
    float a = lsum[0][ch] + lsum[1][ch] + lsum[2][ch] + lsum[3][ch];
    float b = lsq[0][ch] + lsq[1][ch] + lsq[2][ch] + lsq[3][ch];
    psum[blockIdx.x * 512 + ch] = a;
    psq[blockIdx.x * 512 + ch] = b;
  }
}

// ---- finalize BN: 4 blocks x 128 ch ----
__global__ __launch_bounds__(128) void k_bnfin(const float* __restrict__ psum,
                                               const float* __restrict__ psq,
                                               const float* __restrict__ gamma,
                                               const float* __restrict__ beta,
                                               float* __restrict__ scale,
                                               float* __restrict__ shift){
  int ch = blockIdx.x * 128 + threadIdx.x;
  float s0 = 0.f, s1 = 0.f, s2 = 0.f, s3 = 0.f;
  float q0 = 0.f, q1 = 0.f, q2 = 0.f, q3 = 0.f;
  for (int b = 0; b < 256; b += 4){
    s0 += psum[(b    ) * 512 + ch];
    s1 += psum[(b + 1) * 512 + ch];
    s2 += psum[(b + 2) * 512 + ch];
    s3 += psum[(b + 3) * 512 + ch];
    q0 += psq[(b    ) * 512 + ch];
    q1 += psq[(b + 1) * 512 + ch];
    q2 += psq[(b + 2) * 512 + ch];
    q3 += psq[(b + 3) * 512 + ch];
  }
  float sum = (s0 + s1) + (s2 + s3);
  float sq  = (q0 + q1) + (q2 + q3);
  float mu  = sum / (float)N_;
  float var = sq / (float)N_ - mu * mu;
  float inv = rsqrtf(var + 1e-5f);
  float sc  = gamma[ch] * inv;
  scale[ch] = sc;
  shift[ch] = beta[ch] - mu * sc;
}

// ---- GEMM2 (MFMA): out = relu(BN(rst)) @ W_out + b_out, fp32 out ----
__global__ __launch_bounds__(256) void k_gemm2(const unsigned short* __restrict__ comb,
                                               const unsigned short* __restrict__ WtOut,
                                               const float* __restrict__ scale,
                                               const float* __restrict__ shift,
                                               const float* __restrict__ bout,
                                               float* __restrict__ out){
  __shared__ float sc[512], sh[512], bo[128];
  int t = threadIdx.x;
  for (int i = t; i < 512; i += 256){ sc[i] = scale[i]; sh[i] = shift[i]; }
  if (t < 128) bo[t] = bout[t];
  __syncthreads();
  int wave = t >> 6, lane = t & 63, lrow = lane & 15, quad = lane >> 4;
  int rowbase = blockIdx.x * 64 + wave * 16;
  int rr = rowbase + lrow; if (rr > N_ - 1) rr = N_ - 1;
  const unsigned short* arow = comb + rr * 1024 + 512;
  f32x4 acc[8] = {};
#pragma unroll
  for (int kk = 0; kk < 16; kk++){
    int base = kk * 32 + quad * 8;
    Frag a; a.q = *reinterpret_cast<const u32x4*>(arow + base);
#pragma unroll
    for (int i = 0; i < 8; i++){
      float x = b2f(a.us[i]);
      x = fmaf(x, sc[base + i], sh[base + i]);
      a.us[i] = f2b(fmaxf(x, 0.0f));
    }
#pragma unroll
    for (int s = 0; s < 8; s++){
      int col = s * 16 + lrow;
      Frag b; b.q = *reinterpret_cast<const u32x4*>(WtOut + col * 512 + base);
      acc[s] = __builtin_amdgcn_mfma_f32_16x16x32_bf16(a.v, b.v, acc[s], 0, 0, 0);
    }
  }
#pragma unroll
  for (int s = 0; s < 8; s++){
    int col = s * 16 + lrow;
    float bb = bo[col];
#pragma unroll
    for (int j = 0; j < 4; j++){
      int gr = rowbase + quad * 4 + j;
      if (gr < N_) out[gr * 128 + col] = acc[s][j] + bb;
    }
  }
}

extern "C" void kernel_launch(void* const* d_in, const int* in_sizes, int n_in,
                              void* d_out, int out_size, void* d_ws, size_t ws_size,
                              hipStream_t stream){
  const float* feat  = (const float*)d_in[0];
  const int*   src   = (const int*)d_in[1];
  const int*   dst   = (const int*)d_in[2];
  const float* Wfc   = (const float*)d_in[3];
  const float* al    = (const float*)d_in[4];
  const float* ar    = (const float*)d_in[5];
  const float* Wres  = (const float*)d_in[6];
  const float* bias  = (const float*)d_in[7];
  const float* gamma = (const float*)d_in[8];
  const float* beta  = (const float*)d_in[9];
  const float* Wout  = (const float*)d_in[10];
  const float* bout  = (const float*)d_in[11];
  float* out = (float*)d_out;

  char* ws = (char*)d_ws;
  unsigned short* comb   = (unsigned short*)(ws + 0);          // 61,440,000
  unsigned short* Wt     = (unsigned short*)(ws + 61440000);
  unsigned short* WtOut  = (unsigned short*)(ws + 61702144);
  float*          el     = (float*)(ws + 61833216);
  float*          er     = (float*)(ws + 62313216);
  float*          escore = (float*)(ws + 62793216);
  int*            offs   = (int*)(ws + 70473216);
  int*            counts = (int*)(ws + 70593280);
  int*            cursor = (int*)(ws + 70713344);
  int*            eid    = (int*)(ws + 70833408);
  float*          psum   = (float*)(ws + 72753408);
  float*          psq    = (float*)(ws + 73277696);
  float*          scale  = (float*)(ws + 73801984);
  float*          shift  = (float*)(ws + 73804032);
  unsigned short* featb  = (unsigned short*)(ws + 73806080);

  k_initconv<<<640, 256, 0, stream>>>(Wfc, Wres, Wout, feat, Wt, WtOut, featb,
                                      counts, cursor);
  k_hist<<<(E_ + 255) / 256, 256, 0, stream>>>(dst, counts);
  k_scan<<<1, 1024, 0, stream>>>(counts, offs);
  dim3 g1((N_ + 63) / 64, 4);
  k_gemm1<<<g1, 256, 0, stream>>>(featb, Wt, al, ar, comb, el, er);
  k_edge<<<(E_ + 255) / 256, 256, 0, stream>>>(src, dst, el, er, escore, offs, cursor, eid);
  k_aggr<<<(N_ + 1) / 2, 256, 0, stream>>>(offs, eid, src, escore, comb, bias);
  k_stats<<<256, 256, 0, stream>>>(comb, psum, psq);
  k_bnfin<<<4, 128, 0, stream>>>(psum, psq, gamma, beta, scale, shift);
  k_gemm2<<<(N_ + 63) / 64, 256, 0, stream>>>(comb, WtOut, scale, shift, bout, out);
}